// Round 14
// baseline (850.964 us; speedup 1.0000x reference)
//
#include <hip/hip_runtime.h>
#include <hip/hip_bf16.h>
#include <math.h>

#define NTOK 12544
#define DIM 768
#define HID 3072
#define NTILE_MAX 102               // spec 256-row tiles
#define NSLOT_MAX (NTILE_MAX * 256) // 26112 slots
#define NSDT 49                     // NTOK/256 dense row tiles per shared expert
#define NVT (NTILE_MAX + 2 * NSDT)  // 200 virtual 256-row tiles
#define NBKT 64
#define BKTCAP 256
#define LDSB1 49152                 // 128x256 2-phase: A 2x8KB + B 2x16KB
#define NCONVB 6912                 // conv blocks in prep_kernel (576*12)

typedef __hip_bfloat16 bf16;
typedef __attribute__((ext_vector_type(8))) short short8v;
typedef __attribute__((ext_vector_type(4))) float f32x4;

#define GPTR(p)  ((const __attribute__((address_space(1))) void*)(p))
#define LDSPTR(p) ((__attribute__((address_space(3))) void*)(p))

// ---------------------------------------------------------------- prep: conv (bid<NCONVB) + router_ln (else), independent roles
__global__ __launch_bounds__(256) void prep_kernel(
    const float* __restrict__ spec_w1, const float* __restrict__ sh_w1,
    const float* __restrict__ spec_w2, const float* __restrict__ sh_w2,
    bf16* __restrict__ w1t, bf16* __restrict__ w2t,
    int* __restrict__ slot_tok, float* __restrict__ slot_gate,
    const float* __restrict__ x,
    const float* __restrict__ lng, const float* __restrict__ lnb,
    const float* __restrict__ srw, const float* __restrict__ srb,
    const float* __restrict__ shw, const float* __restrict__ shb,
    bf16* __restrict__ xnb,
    float* __restrict__ spec_logits, float* __restrict__ spec_probs,
    float* __restrict__ topk_idx, float* __restrict__ topk_probs,
    float* __restrict__ sh_logits, float* __restrict__ sh_probs,
    float* __restrict__ gates,
    int* __restrict__ cnt2, int* __restrict__ tok2, float* __restrict__ gate2) {
    __shared__ float tile[64][65];
    int bid = blockIdx.x;
    int t = threadIdx.x;
    if (bid < NCONVB) {
        // ---------------- conv role: transpose + f32->bf16
        int z = bid / 576, ti = bid % 576;
        if (z == 0 && ti < NTILE_MAX) {
            int s = ti * 256 + t;
            slot_tok[s] = 0; slot_gate[s] = 0.0f;
        }
        const float* src; bf16* dst; int R, C, tr, tc;
        if (z < 6) {
            R = DIM; C = HID;
            src = (z < 4) ? spec_w1 + (size_t)z * R * C : sh_w1 + (size_t)(z - 4) * R * C;
            dst = w1t + (size_t)z * R * C;
            tr = ti % 12; tc = ti / 12;
        } else {
            int e = z - 6;
            R = HID; C = DIM;
            src = (e < 4) ? spec_w2 + (size_t)e * R * C : sh_w2 + (size_t)(e - 4) * R * C;
            dst = w2t + (size_t)e * R * C;
            tr = ti % 48; tc = ti / 48;
        }
        int r0 = tr * 64, c0 = tc * 64;
        int lr = t >> 4, lc = (t & 15) * 4;
        #pragma unroll
        for (int ii = 0; ii < 4; ++ii) {
            float4 v = *(const float4*)&src[(size_t)(r0 + lr + 16 * ii) * C + c0 + lc];
            tile[lc + 0][lr + 16 * ii] = v.x;
            tile[lc + 1][lr + 16 * ii] = v.y;
            tile[lc + 2][lr + 16 * ii] = v.z;
            tile[lc + 3][lr + 16 * ii] = v.w;
        }
        __syncthreads();
        int oc = t >> 4, orr = (t & 15) * 4;
        #pragma unroll
        for (int ii = 0; ii < 4; ++ii) {
            union { ushort4 u4; bf16 h[4]; } pk;
            #pragma unroll
            for (int k = 0; k < 4; ++k)
                pk.h[k] = __float2bfloat16(tile[oc + 16 * ii][orr + k]);
            *(ushort4*)&dst[(size_t)(c0 + oc + 16 * ii) * R + r0 + orr] = pk.u4;
        }
        return;
    }
    // ---------------- router role
    int rid = bid - NCONVB;
    int tok = rid * 4 + (t >> 6);
    int bucket = rid & (NBKT - 1);
    int lane = t & 63;
    const float* xr = x + (size_t)tok * DIM;
    bf16* xb = xnb + (size_t)tok * DIM;
    float v[12];
    float s = 0.0f;
    #pragma unroll
    for (int i = 0; i < 6; ++i) {
        float2 xv = *(const float2*)&xr[lane * 2 + 128 * i];
        v[2 * i] = xv.x; v[2 * i + 1] = xv.y;
        s += xv.x + xv.y;
    }
    #pragma unroll
    for (int o = 32; o > 0; o >>= 1) s += __shfl_xor(s, o, 64);
    float mean = s * (1.0f / 768.0f);
    float sq = 0.0f;
    #pragma unroll
    for (int i = 0; i < 12; ++i) { float d = v[i] - mean; sq += d * d; }
    #pragma unroll
    for (int o = 32; o > 0; o >>= 1) sq += __shfl_xor(sq, o, 64);
    float rstd = rsqrtf(sq * (1.0f / 768.0f) + 1e-5f);

    float acc[6] = {0, 0, 0, 0, 0, 0};
    #pragma unroll
    for (int i = 0; i < 6; ++i) {
        int d0 = lane * 2 + 128 * i;
        float xn0 = (v[2 * i]     - mean) * rstd * lng[d0]     + lnb[d0];
        float xn1 = (v[2 * i + 1] - mean) * rstd * lng[d0 + 1] + lnb[d0 + 1];
        union { unsigned u; bf16 h[2]; } pk;
        pk.h[0] = __float2bfloat16(xn0);
        pk.h[1] = __float2bfloat16(xn1);
        *(unsigned*)&xb[d0] = pk.u;
        float4 a = *(const float4*)&srw[d0 * 4];
        float4 b = *(const float4*)&srw[d0 * 4 + 4];
        acc[0] += xn0 * a.x + xn1 * b.x;
        acc[1] += xn0 * a.y + xn1 * b.y;
        acc[2] += xn0 * a.z + xn1 * b.z;
        acc[3] += xn0 * a.w + xn1 * b.w;
        float4 sw = *(const float4*)&shw[d0 * 2];
        acc[4] += xn0 * sw.x + xn1 * sw.z;
        acc[5] += xn0 * sw.y + xn1 * sw.w;
    }
    #pragma unroll
    for (int j = 0; j < 6; ++j) {
        #pragma unroll
        for (int o = 32; o > 0; o >>= 1) acc[j] += __shfl_xor(acc[j], o, 64);
    }
    if (lane == 0) {
        float l[4];
        #pragma unroll
        for (int j = 0; j < 4; ++j) l[j] = acc[j] + srb[j];
        float m = fmaxf(fmaxf(l[0], l[1]), fmaxf(l[2], l[3]));
        float e[4], ssum = 0.0f;
        #pragma unroll
        for (int j = 0; j < 4; ++j) { e[j] = expf(l[j] - m); ssum += e[j]; }
        float inv = 1.0f / ssum;
        float p[4];
        #pragma unroll
        for (int j = 0; j < 4; ++j) p[j] = e[j] * inv;
        int i0 = 0;
        for (int j = 1; j < 4; ++j) if (p[j] > p[i0]) i0 = j;
        int i1 = -1;
        for (int j = 0; j < 4; ++j) {
            if (j == i0) continue;
            if (i1 < 0 || p[j] > p[i1]) i1 = j;
        }
        float sl0 = acc[4] + shb[0], sl1 = acc[5] + shb[1];
        float sm = fmaxf(sl0, sl1);
        float se0 = expf(sl0 - sm), se1 = expf(sl1 - sm);
        float sinv = 1.0f / (se0 + se1);
        float sp0 = se0 * sinv, sp1 = se1 * sinv;

        #pragma unroll
        for (int j = 0; j < 4; ++j) {
            spec_logits[tok * 4 + j] = l[j];
            spec_probs[tok * 4 + j]  = p[j];
        }
        topk_idx[tok * 2 + 0]   = (float)i0;
        topk_idx[tok * 2 + 1]   = (float)i1;
        topk_probs[tok * 2 + 0] = p[i0];
        topk_probs[tok * 2 + 1] = p[i1];
        sh_logits[tok * 2 + 0]  = sl0;
        sh_logits[tok * 2 + 1]  = sl1;
        sh_probs[tok * 2 + 0]   = sp0;
        sh_probs[tok * 2 + 1]   = sp1;
        float gg[6] = {0, 0, 0, 0, sp0, sp1};
        gg[i0] = p[i0];
        gg[i1] = p[i1];
        #pragma unroll
        for (int j = 0; j < 6; ++j) gates[tok * 6 + j] = gg[j];
        int c0 = i0 * NBKT + bucket;
        int pos0 = atomicAdd(&cnt2[c0], 1);
        tok2[c0 * BKTCAP + pos0]  = tok * 2 + 0;
        gate2[c0 * BKTCAP + pos0] = p[i0];
        int c1 = i1 * NBKT + bucket;
        int pos1 = atomicAdd(&cnt2[c1], 1);
        tok2[c1 * BKTCAP + pos1]  = tok * 2 + 1;
        gate2[c1 * BKTCAP + pos1] = p[i1];
    }
}

// ---------------------------------------------------------------- plan: bucket scan, 256-row padded compact
__global__ void plan_kernel(const int* __restrict__ cnt2, int* __restrict__ e_of_tile,
                            const int* __restrict__ tok2, const float* __restrict__ gate2,
                            int* __restrict__ slot_tok, float* __restrict__ slot_gate,
                            int* __restrict__ back) {
    __shared__ int sbase[4 * NBKT];
    __shared__ int offsE[5];
    __shared__ int etot[4];
    int tid = threadIdx.x, lane = tid & 63, wid = tid >> 6;
    int c = cnt2[wid * NBKT + lane];
    int inc = c;
    #pragma unroll
    for (int o = 1; o < 64; o <<= 1) {
        int tv = __shfl_up(inc, o, 64);
        if (lane >= o) inc += tv;
    }
    int exc = inc - c;
    if (lane == 63) etot[wid] = inc;
    __syncthreads();
    if (tid == 0) {
        int o = 0;
        for (int e = 0; e < 4; ++e) { offsE[e] = o; o += (etot[e] + 255) & ~255; }
        offsE[4] = o;
    }
    __syncthreads();
    sbase[tid] = offsE[wid] + exc;
    for (int idx = tid; idx < NTILE_MAX; idx += 256) {
        int s0 = idx * 256, e = -1;
        for (int j = 0; j < 4; ++j)
            if (s0 >= offsE[j] && s0 < offsE[j + 1]) e = j;
        e_of_tile[idx] = e;
    }
    __syncthreads();
    int bs = sbase[tid];
    int cc = cnt2[tid];
    for (int i = 0; i < cc; ++i) {
        int gs = bs + i;
        int tk = tok2[tid * BKTCAP + i];
        slot_tok[gs] = tk >> 1;
        slot_gate[gs] = gate2[tid * BKTCAP + i];
        back[tk] = gs;
    }
}

// ---------------------------------------------------------------- gather: pack spec-slot A rows into xg (aliased w/ spec_g)
__global__ void gather_kernel(const bf16* __restrict__ xnb, const int* __restrict__ slot_tok,
                              bf16* __restrict__ xg) {
    int idx = blockIdx.x * 256 + threadIdx.x;
    int slot = idx / 96;
    int c = (idx % 96) * 8;
    int tok = slot_tok[slot];
    *(short8v*)&xg[(size_t)slot * DIM + c] = *(const short8v*)&xnb[(size_t)tok * DIM + c];
}

// ================================================================ shared MFMA helpers
__device__ __forceinline__ int swz(int off) {
    return off ^ (((off >> 8) & 1) << 4) ^ (((off >> 9) & 1) << 5);
}

__device__ __forceinline__ void stage2(bf16* lds, int base_elems, int wid,
                                       const bf16* s0, const bf16* s1) {
    __builtin_amdgcn_global_load_lds(GPTR(s0), LDSPTR(lds + base_elems + wid * 512), 16, 0, 0);
    __builtin_amdgcn_global_load_lds(GPTR(s1), LDSPTR(lds + base_elems + 4096 + wid * 512), 16, 0, 0);
}

__device__ __forceinline__ void mfma16(const short8v a[4], const short8v b[4], f32x4 (*am)[4]) {
    #pragma unroll
    for (int i = 0; i < 4; ++i)
        #pragma unroll
        for (int j = 0; j < 4; ++j)
            am[i][j] = __builtin_amdgcn_mfma_f32_16x16x32_bf16(a[i], b[j], am[i][j], 0, 0, 0);
}

#define BARRIER() __builtin_amdgcn_s_barrier()
#define VMCNT3() asm volatile("s_waitcnt vmcnt(3)" ::: "memory")
#define VMCNT0() asm volatile("s_waitcnt vmcnt(0)" ::: "memory")

// ================================================================ 128x256 2-phase core (both GEMMs)
// LDS (bytes): A slot s at s*8192 ([128][32] bf16); B slot s at 16384 + s*16384
// ([256][32] bf16). Double-XOR swizzle; counted vmcnt(3).
__device__ __forceinline__ void read_a4_128(const bf16* lds, int cur, int wm,
                                            int lane, short8v a[4]) {
    const char* base = (const char*)lds + cur * 8192;
    #pragma unroll
    for (int i = 0; i < 4; ++i) {
        int off = (wm * 64 + i * 16 + (lane & 15)) * 64 + ((lane >> 4) * 16);
        a[i] = *(const short8v*)(base + swz(off));
    }
}

__device__ __forceinline__ void read_b4_128(const bf16* lds, int cur, int wn,
                                            int lane, short8v b[4]) {
    const char* base = (const char*)lds + 16384 + cur * 16384;
    #pragma unroll
    for (int j = 0; j < 4; ++j) {
        int off = (wn * 64 + j * 16 + (lane & 15)) * 64 + ((lane >> 4) * 16);
        b[j] = *(const short8v*)(base + swz(off));
    }
}

template<int NS>
__device__ __forceinline__ void kloop2p(bf16* lds, const bf16* aA,
                                        const bf16* b0, const bf16* b1,
                                        int wm, int wn, int wid, int lane,
                                        f32x4 acc[4][4]) {
    __builtin_amdgcn_global_load_lds(GPTR(aA), LDSPTR(lds + wid * 512), 16, 0, 0);
    stage2(lds, 8192, wid, b0, b1);
    for (int s = 0; s < NS; ++s) {
        int cur = s & 1, nb = cur ^ 1;
        bool pre = (s + 1 < NS);
        if (pre) {
            __builtin_amdgcn_global_load_lds(GPTR(aA + (s + 1) * 32),
                                             LDSPTR(lds + nb * 4096 + wid * 512), 16, 0, 0);
            stage2(lds, 8192 + nb * 8192, wid, b0 + (s + 1) * 32, b1 + (s + 1) * 32);
        }
        if (pre) VMCNT3(); else VMCNT0();
        BARRIER();
        short8v av[4], bv[4];
        read_a4_128(lds, cur, wm, lane, av);
        read_b4_128(lds, cur, wn, lane, bv);
        __builtin_amdgcn_s_setprio(1);
        mfma16(av, bv, &acc[0]);
        __builtin_amdgcn_s_setprio(0);
        BARRIER();
    }
}

__device__ __forceinline__ float gelu_exact(float v) {
    return 0.5f * v * (1.0f + erff(v * 0.70710678118654752f));
}

// fast exact-GELU: A&S 7.1.26 erf (|err|<1.5e-7) + hw exp/rcp
__device__ __forceinline__ float gelu_fast(float x) {
    float z = 0.70710678118654752f * x;
    float az = fabsf(z);
    float t = __builtin_amdgcn_rcpf(1.0f + 0.3275911f * az);
    float poly = t * (0.254829592f + t * (-0.284496736f + t * (1.421413741f +
                 t * (-1.453152027f + t * 1.061405429f))));
    float erfv = 1.0f - poly * __expf(-az * az);
    erfv = (z < 0.0f) ? -erfv : erfv;
    return 0.5f * x * (1.0f + erfv);
}

// ---------------------------------------------------------------- GEMM1 2-phase 128x256 (refcheck'd R13)
__global__ __launch_bounds__(512, 4) void gemm1_2p(
    const bf16* __restrict__ xg, const bf16* __restrict__ xnb,
    const bf16* __restrict__ w1t,
    const float* __restrict__ spec_b1, const float* __restrict__ sh_b1,
    const int* __restrict__ e_of_tile,
    bf16* __restrict__ Hbuf, int y_base) {
    extern __shared__ bf16 lds[];
    int bx = blockIdx.x, by = blockIdx.y;
    int lt = by >> 1, half = by & 1;
    int y = y_base + lt;
    int tid = threadIdx.x, wid = tid >> 6, lane = tid & 63;
    int wm = wid >> 2, wn = wid & 3;
    int PA = tid;
    int LA = PA ^ ((PA >> 4) & 1) ^ (((PA >> 5) & 1) << 1);
    int ra = LA >> 2, ca = (LA & 3) * 8;
    int P0c = tid, P1c = 512 + tid;
    int L0 = P0c ^ ((P0c >> 4) & 1) ^ (((P0c >> 5) & 1) << 1);
    int L1 = P1c ^ ((P1c >> 4) & 1) ^ (((P1c >> 5) & 1) << 1);
    int rb0 = L0 >> 2, cb0 = (L0 & 3) * 8;
    int rb1 = L1 >> 2, cb1 = (L1 & 3) * 8;

    const bf16 *abase, *Bw;
    const float* bias;
    if (y < NTILE_MAX) {
        int e = e_of_tile[y];
        if (e < 0) return;
        abase = xg + (size_t)(y * 256 + half * 128) * DIM;
        Bw = w1t + (size_t)e * HID * DIM;
        bias = spec_b1 + (size_t)e * HID;
    } else {
        int ys = y - NTILE_MAX;
        int z = ys / NSDT, ry = ys % NSDT;
        abase = xnb + (size_t)(ry * 256 + half * 128) * DIM;
        Bw = w1t + (size_t)(4 + z) * HID * DIM;
        bias = sh_b1 + (size_t)z * HID;
    }
    const bf16* aA = abase + (size_t)ra * DIM + ca;
    const bf16* b0 = Bw + (size_t)(bx * 256 + rb0) * DIM + cb0;
    const bf16* b1 = Bw + (size_t)(bx * 256 + rb1) * DIM + cb1;

    f32x4 acc[4][4] = {};
    kloop2p<DIM / 32>(lds, aA, b0, b1, wm, wn, wid, lane, acc);

    bf16* hb = Hbuf + (size_t)(lt * 256 + half * 128) * HID;
    int fr = lane & 15, fq = lane >> 4;
    int cb = bx * 256 + wn * 64;
    #pragma unroll
    for (int j = 0; j < 4; ++j) {
        int col = cb + j * 16 + fr;
        float bv = bias[col];
        #pragma unroll
        for (int i = 0; i < 4; ++i) {
            #pragma unroll
            for (int rr = 0; rr < 4; ++rr) {
                int row = wm * 64 + i * 16 + fq * 4 + rr;
                hb[(size_t)row * HID + col] = __float2bfloat16(gelu_fast(acc[i][j][rr] + bv));
            }
        }
    }
}

// ---------------------------------------------------------------- GEMM2 2-phase 128x256 (NEW: same core, K=3072, gate epilogue)
__global__ __launch_bounds__(512, 4) void gemm2_2p(
    const bf16* __restrict__ Hbuf, const bf16* __restrict__ w2t,
    const float* __restrict__ spec_b2, const float* __restrict__ sh_b2,
    const int* __restrict__ e_of_tile, const float* __restrict__ slot_gate,
    const float* __restrict__ sh_probs,
    bf16* __restrict__ spec_g, bf16* __restrict__ shg, int y_base) {
    extern __shared__ bf16 lds[];
    int bx = blockIdx.x, by = blockIdx.y;
    int lt = by >> 1, half = by & 1;
    int y = y_base + lt;
    int tid = threadIdx.x, wid = tid >> 6, lane = tid & 63;
    int wm = wid >> 2, wn = wid & 3;
    int PA = tid;
    int LA = PA ^ ((PA >> 4) & 1) ^ (((PA >> 5) & 1) << 1);
    int ra = LA >> 2, ca = (LA & 3) * 8;
    int P0c = tid, P1c = 512 + tid;
    int L0 = P0c ^ ((P0c >> 4) & 1) ^ (((P0c >> 5) & 1) << 1);
    int L1 = P1c ^ ((P1c >> 4) & 1) ^ (((P1c >> 5) & 1) << 1);
    int rb0 = L0 >> 2, cb0 = (L0 & 3) * 8;
    int rb1 = L1 >> 2, cb1 = (L1 & 3) * 8;

    const bf16* Bw;
    const float* bias;
    bf16* obase;
    bool grouped = (y < NTILE_MAX);
    int z = 0, ry = 0;
    if (grouped) {
        int e = e_of_tile[y];
        if (e < 0) return;
        Bw = w2t + (size_t)e * DIM * HID;
        bias = spec_b2 + (size_t)e * DIM;
        obase = spec_g + (size_t)(y * 256 + half * 128) * DIM;
    } else {
        int ys = y - NTILE_MAX;
        z = ys / NSDT; ry = ys % NSDT;
        Bw = w2t + (size_t)(4 + z) * DIM * HID;
        bias = sh_b2 + (size_t)z * DIM;
        obase = shg + (size_t)(z * NTOK + ry * 256 + half * 128) * DIM;
    }
    const bf16* Ah = Hbuf + (size_t)(lt * 256 + half * 128) * HID;
    const bf16* aA = Ah + (size_t)ra * HID + ca;
    const bf16* b0 = Bw + (size_t)(bx * 256 + rb0) * HID + cb0;
    const bf16* b1 = Bw + (size_t)(bx * 256 + rb1) * HID + cb1;

    f32x4 acc[4][4] = {};
    kloop2p<HID / 32>(lds, aA, b0, b1, wm, wn, wid, lane, acc);

    int fr = lane & 15, fq = lane >> 4;
    int cb = bx * 256 + wn * 64;
    int rowbase = half * 128;
    #pragma unroll
    for (int j = 0; j < 4; ++j) {
        int col = cb + j * 16 + fr;
        float bv = bias[col];
        #pragma unroll
        for (int i = 0; i < 4; ++i) {
            #pragma unroll
            for (int rr = 0; rr < 4; ++rr) {
                int row = wm * 64 + i * 16 + fq * 4 + rr;
                float g = grouped ? slot_gate[y * 256 + rowbase + row]
                                  : sh_probs[(size_t)(ry * 256 + rowbase + row) * 2 + z];
                obase[(size_t)row * DIM + col] = __float2bfloat16(g * (acc[i][j][rr] + bv));
            }
        }
    }
}

// ---------------------------------------------------------------- plan-B dense fallback (128^2 m97, known-good)
__device__ __forceinline__ void stage_tile(const bf16* __restrict__ g, int ldg,
                                           bf16* lds, int tid) {
    int wave = tid >> 6, lane = tid & 63;
    #pragma unroll
    for (int q = 0; q < 2; ++q) {
        int chunk = wave * 2 + q;
        int row = chunk * 16 + (lane >> 2);
        int col = (lane & 3) * 8;
        __builtin_amdgcn_global_load_lds(GPTR(g + (size_t)row * ldg + col),
                                         LDSPTR(lds + chunk * 512), 16, 0, 0);
    }
}

__device__ __forceinline__ void mfma_step(const bf16* As, const bf16* Bs,
                                          int wr, int wc, int fr, int fq, f32x4 acc[4][4]) {
    short8v a[4], b[4];
    #pragma unroll
    for (int i = 0; i < 4; ++i) {
        a[i] = *(const short8v*)&As[(wr * 64 + i * 16 + fr) * 32 + fq * 8];
        b[i] = *(const short8v*)&Bs[(wc * 64 + i * 16 + fr) * 32 + fq * 8];
    }
    #pragma unroll
    for (int i = 0; i < 4; ++i)
        #pragma unroll
        for (int j = 0; j < 4; ++j)
            acc[i][j] = __builtin_amdgcn_mfma_f32_16x16x32_bf16(a[i], b[j], acc[i][j], 0, 0, 0);
}

__global__ __launch_bounds__(256) void gemm1_dense(
    const bf16* __restrict__ A, const bf16* __restrict__ BT,
    const float* __restrict__ bias, bf16* __restrict__ H) {
    __shared__ bf16 As[128 * 32];
    __shared__ bf16 Bs[128 * 32];
    int tid = threadIdx.x;
    int wid = tid >> 6, lane = tid & 63;
    int wr = wid >> 1, wc = wid & 1;
    int fr = lane & 15, fq = lane >> 4;
    const bf16* Ag = A + (size_t)(blockIdx.y * 128) * DIM;
    const bf16* Bg = BT + (size_t)(blockIdx.x * 128) * DIM;
    f32x4 acc[4][4] = {};
    for (int k0 = 0; k0 < DIM; k0 += 32) {
        stage_tile(Ag + k0, DIM, As, tid);
        stage_tile(Bg + k0, DIM, Bs, tid);
        __syncthreads();
        mfma_step(As, Bs, wr, wc, fr, fq, acc);
        __syncthreads();
    }
    int rbase = blockIdx.y * 128 + wr * 64;
    int cbase = blockIdx.x * 128 + wc * 64;
    #pragma unroll
    for (int j = 0; j < 4; ++j) {
        int col = cbase + j * 16 + fr;
        float bv = bias[col];
        #pragma unroll
        for (int i = 0; i < 4; ++i)
            #pragma unroll
            for (int r = 0; r < 4; ++r) {
                int row = rbase + i * 16 + fq * 4 + r;
                H[(size_t)row * HID + col] = __float2bfloat16(gelu_exact(acc[i][j][r] + bv));
            }
    }
}

__global__ __launch_bounds__(256) void gemm2_dense_out(
    const bf16* __restrict__ A, const bf16* __restrict__ BT,
    const float* __restrict__ bias, const float* __restrict__ gates,
    float* __restrict__ out, int gidx, int accum) {
    __shared__ bf16 As[128 * 32];
    __shared__ bf16 Bs[128 * 32];
    int tid = threadIdx.x;
    int wid = tid >> 6, lane = tid & 63;
    int wr = wid >> 1, wc = wid & 1;
    int fr = lane & 15, fq = lane >> 4;
    const bf16* Ag = A + (size_t)(blockIdx.y * 128) * HID;
    const bf16* Bg = BT + (size_t)(blockIdx.x * 128) * HID;
    f32x4 acc[4][4] = {};
    for (int k0 = 0; k0 < HID; k0 += 32) {
        stage_tile(Ag + k0, HID, As, tid);
        stage_tile(Bg + k0, HID, Bs, tid);
        __syncthreads();
        mfma_step(As, Bs, wr, wc, fr, fq, acc);
        __syncthreads();
    }
    int rbase = blockIdx.y * 128 + wr * 64;
    int cbase = blockIdx.x * 128 + wc * 64;
    #pragma unroll
    for (int j = 0; j < 4; ++j) {
        int col = cbase + j * 16 + fr;
        float bv = bias[col];
        #pragma unroll
        for (int i = 0; i < 4; ++i)
            #pragma unroll
            for (int r = 0; r < 4; ++r) {
                int row = rbase + i * 16 + fq * 4 + r;
                float g = gates[(size_t)row * 6 + gidx];
                float v = g * (acc[i][j][r] + bv);
                size_t idx = (size_t)row * DIM + col;
                out[idx] = accum ? out[idx] + v : v;
            }
    }
}

// ---------------------------------------------------------------- combine
__global__ void combine_kernel(const bf16* __restrict__ spec_g, const bf16* __restrict__ shg,
                               const int* __restrict__ back, float* __restrict__ out) {
    int idx = blockIdx.x * 256 + threadIdx.x;
    int tok = idx / 96;
    int c = (idx % 96) * 8;
    int b0 = back[2 * tok], b1 = back[2 * tok + 1];
    short8v q0 = *(const short8v*)&spec_g[(size_t)b0 * DIM + c];
    short8v q1 = *(const short8v*)&spec_g[(size_t)b1 * DIM + c];
    short8v s0 = *(const short8v*)&shg[(size_t)tok * DIM + c];
    short8v s1 = *(const short8v*)&shg[(size_t)(NTOK + tok) * DIM + c];
    float o[8];
    #pragma unroll
    for (int k = 0; k < 8; ++k) {
        float f0 = __uint_as_float((unsigned)(unsigned short)q0[k] << 16);
        float f1 = __uint_as_float((unsigned)(unsigned short)q1[k] << 16);
        float f2 = __uint_as_float((unsigned)(unsigned short)s0[k] << 16);
        float f3 = __uint_as_float((unsigned)(unsigned short)s1[k] << 16);
        o[k] = f0 + f1 + f2 + f3;
    }
    float* op = out + (size_t)tok * DIM + c;
    *(float4*)(op)     = *(const float4*)(o);
    *(float4*)(op + 4) = *(const float4*)(o + 4);
}

// ---------------------------------------------------------------- launch
static inline size_t align256(size_t x) { return (x + 255) & ~(size_t)255; }

extern "C" void kernel_launch(void* const* d_in, const int* in_sizes, int n_in,
                              void* d_out, int out_size, void* d_ws, size_t ws_size,
                              hipStream_t stream) {
    const float* x      = (const float*)d_in[0];
    const float* gamma  = (const float*)d_in[1];
    const float* beta   = (const float*)d_in[2];
    const float* srw    = (const float*)d_in[3];
    const float* srb    = (const float*)d_in[4];
    const float* spec_w1 = (const float*)d_in[5];
    const float* spec_b1 = (const float*)d_in[6];
    const float* spec_w2 = (const float*)d_in[7];
    const float* spec_b2 = (const float*)d_in[8];
    const float* shw    = (const float*)d_in[9];
    const float* shb    = (const float*)d_in[10];
    const float* sh_w1  = (const float*)d_in[11];
    const float* sh_b1  = (const float*)d_in[12];
    const float* sh_w2  = (const float*)d_in[13];
    const float* sh_b2  = (const float*)d_in[14];

    char* p = (char*)d_ws;
    size_t off = 0;
    bf16* xnb = (bf16*)(p + off);       off = align256(off + (size_t)NTOK * DIM * 2);
    bf16* w1t = (bf16*)(p + off);       off = align256(off + (size_t)6 * HID * DIM * 2);
    bf16* w2t = (bf16*)(p + off);       off = align256(off + (size_t)6 * DIM * HID * 2);
    int*  cnt2 = (int*)(p + off);       off = align256(off + (size_t)4 * NBKT * 4);
    float* gates = (float*)(p + off);   off = align256(off + (size_t)NTOK * 6 * 4);
    int*  tok2 = (int*)(p + off);       off = align256(off + (size_t)4 * NBKT * BKTCAP * 4);
    float* gate2 = (float*)(p + off);   off = align256(off + (size_t)4 * NBKT * BKTCAP * 4);
    int*  slot_tok = (int*)(p + off);   off = align256(off + (size_t)NSLOT_MAX * 4);
    float* slot_gate = (float*)(p + off); off = align256(off + (size_t)NSLOT_MAX * 4);
    int*  back = (int*)(p + off);       off = align256(off + (size_t)2 * NTOK * 4);
    int*  e_of_tile = (int*)(p + off);  off = align256(off + (size_t)NTILE_MAX * 4);
    bf16* spec_g = (bf16*)(p + off);    off = align256(off + (size_t)NSLOT_MAX * DIM * 2);
    bf16* shg   = (bf16*)(p + off);     off = align256(off + (size_t)2 * NTOK * DIM * 2);
    size_t fixed_end = off;
    bf16* Hbuf = (bf16*)(p + fixed_end);
    bf16* xg = spec_g;   // aliased: gather-write -> g1 read -> g2 write -> combine read

    const size_t tile_bytes = (size_t)256 * HID * 2;
    size_t avail = (ws_size > fixed_end) ? (ws_size - fixed_end) : 0;
    int tcap = (int)(avail / tile_bytes);
    if (tcap > NVT) tcap = NVT;

    float* out         = (float*)d_out;
    float* spec_logits = out + (size_t)NTOK * DIM;
    float* spec_probs  = spec_logits + (size_t)NTOK * 4;
    float* topk_idx    = spec_probs  + (size_t)NTOK * 4;
    float* topk_probs  = topk_idx    + (size_t)NTOK * 2;
    float* sh_logits   = topk_probs  + (size_t)NTOK * 2;
    float* sh_probs    = sh_logits   + (size_t)NTOK * 2;

    hipMemsetAsync(cnt2, 0, (size_t)4 * NBKT * 4, stream);
    prep_kernel<<<NCONVB + NTOK / 4, 256, 0, stream>>>(
        spec_w1, sh_w1, spec_w2, sh_w2, w1t, w2t, slot_tok, slot_gate,
        x, gamma, beta, srw, srb, shw, shb, xnb,
        spec_logits, spec_probs, topk_idx, topk_probs, sh_logits, sh_probs,
        gates, cnt2, tok2, gate2);

    if (tcap >= 8) {
        plan_kernel<<<1, 256, 0, stream>>>(cnt2, e_of_tile, tok2, gate2,
                                           slot_tok, slot_gate, back);
        gather_kernel<<<NSLOT_MAX * 96 / 256, 256, 0, stream>>>(xnb, slot_tok, xg);
        int csz = tcap >= 67 ? (NVT + 2) / 3 : (tcap < 64 ? tcap : 64);
        if (csz > tcap) csz = tcap;
        for (int c0 = 0; c0 < NVT; c0 += csz) {
            int n = NVT - c0 < csz ? NVT - c0 : csz;
            gemm1_2p<<<dim3(HID / 256, 2 * n), 512, LDSB1, stream>>>(
                xg, xnb, w1t, spec_b1, sh_b1, e_of_tile, Hbuf, c0);
            gemm2_2p<<<dim3(DIM / 256, 2 * n), 512, LDSB1, stream>>>(
                Hbuf, w2t, spec_b2, sh_b2, e_of_tile, slot_gate, sh_probs,
                spec_g, shg, c0);
        }
        combine_kernel<<<NTOK * 96 / 256, 256, 0, stream>>>(spec_g, shg, back, out);
    } else {
        // plan B: dense 6-expert loop (reuses spec_g/shg region as H)
        bf16* HB = spec_g;
        for (int e = 0; e < 6; ++e) {
            const bf16* w1p = w1t + (size_t)e * HID * DIM;
            const bf16* w2p = w2t + (size_t)e * DIM * HID;
            const float* b1p = (e < 4) ? spec_b1 + (size_t)e * HID : sh_b1 + (size_t)(e - 4) * HID;
            const float* b2p = (e < 4) ? spec_b2 + (size_t)e * DIM : sh_b2 + (size_t)(e - 4) * DIM;
            gemm1_dense<<<dim3(HID / 128, NTOK / 128), 256, 0, stream>>>(xnb, w1p, b1p, HB);
            gemm2_dense_out<<<dim3(DIM / 128, NTOK / 128), 256, 0, stream>>>(
                HB, w2p, b2p, gates, out, e, e > 0);
        }
    }
}

// Round 15
// 837.531 us; speedup vs baseline: 1.0160x; 1.0160x over previous
//
#include <hip/hip_runtime.h>
#include <hip/hip_bf16.h>
#include <math.h>

#define NTOK 12544
#define DIM 768
#define HID 3072
#define NTILE_MAX 102               // spec 256-row tiles
#define NSLOT_MAX (NTILE_MAX * 256) // 26112 slots
#define NSDT 49                     // NTOK/256 dense row tiles per shared expert
#define NVT (NTILE_MAX + 2 * NSDT)  // 200 virtual 256-row tiles
#define NBKT 64
#define BKTCAP 256
#define LDSB 131072                 // gemm2 (256x256 8-phase)
#define LDSB1 49152                 // gemm1 (128x256 2-phase)
#define NCONVB 6912                 // conv blocks in prep_kernel (576*12)

typedef __hip_bfloat16 bf16;
typedef __attribute__((ext_vector_type(8))) short short8v;
typedef __attribute__((ext_vector_type(4))) float f32x4;

#define GPTR(p)  ((const __attribute__((address_space(1))) void*)(p))
#define LDSPTR(p) ((__attribute__((address_space(3))) void*)(p))

// ---------------------------------------------------------------- prep: conv (bid<NCONVB) + router_ln (else)
__global__ __launch_bounds__(256) void prep_kernel(
    const float* __restrict__ spec_w1, const float* __restrict__ sh_w1,
    const float* __restrict__ spec_w2, const float* __restrict__ sh_w2,
    bf16* __restrict__ w1t, bf16* __restrict__ w2t,
    int* __restrict__ slot_tok, float* __restrict__ slot_gate,
    const float* __restrict__ x,
    const float* __restrict__ lng, const float* __restrict__ lnb,
    const float* __restrict__ srw, const float* __restrict__ srb,
    const float* __restrict__ shw, const float* __restrict__ shb,
    bf16* __restrict__ xnb,
    float* __restrict__ spec_logits, float* __restrict__ spec_probs,
    float* __restrict__ topk_idx, float* __restrict__ topk_probs,
    float* __restrict__ sh_logits, float* __restrict__ sh_probs,
    float* __restrict__ gates,
    int* __restrict__ cnt2, int* __restrict__ tok2, float* __restrict__ gate2) {
    __shared__ float tile[64][65];
    int bid = blockIdx.x;
    int t = threadIdx.x;
    if (bid < NCONVB) {
        int z = bid / 576, ti = bid % 576;
        if (z == 0 && ti < NTILE_MAX) {
            int s = ti * 256 + t;
            slot_tok[s] = 0; slot_gate[s] = 0.0f;
        }
        const float* src; bf16* dst; int R, C, tr, tc;
        if (z < 6) {
            R = DIM; C = HID;
            src = (z < 4) ? spec_w1 + (size_t)z * R * C : sh_w1 + (size_t)(z - 4) * R * C;
            dst = w1t + (size_t)z * R * C;
            tr = ti % 12; tc = ti / 12;
        } else {
            int e = z - 6;
            R = HID; C = DIM;
            src = (e < 4) ? spec_w2 + (size_t)e * R * C : sh_w2 + (size_t)(e - 4) * R * C;
            dst = w2t + (size_t)e * R * C;
            tr = ti % 48; tc = ti / 48;
        }
        int r0 = tr * 64, c0 = tc * 64;
        int lr = t >> 4, lc = (t & 15) * 4;
        #pragma unroll
        for (int ii = 0; ii < 4; ++ii) {
            float4 v = *(const float4*)&src[(size_t)(r0 + lr + 16 * ii) * C + c0 + lc];
            tile[lc + 0][lr + 16 * ii] = v.x;
            tile[lc + 1][lr + 16 * ii] = v.y;
            tile[lc + 2][lr + 16 * ii] = v.z;
            tile[lc + 3][lr + 16 * ii] = v.w;
        }
        __syncthreads();
        int oc = t >> 4, orr = (t & 15) * 4;
        #pragma unroll
        for (int ii = 0; ii < 4; ++ii) {
            union { ushort4 u4; bf16 h[4]; } pk;
            #pragma unroll
            for (int k = 0; k < 4; ++k)
                pk.h[k] = __float2bfloat16(tile[oc + 16 * ii][orr + k]);
            *(ushort4*)&dst[(size_t)(c0 + oc + 16 * ii) * R + r0 + orr] = pk.u4;
        }
        return;
    }
    int rid = bid - NCONVB;
    int tok = rid * 4 + (t >> 6);
    int bucket = rid & (NBKT - 1);
    int lane = t & 63;
    const float* xr = x + (size_t)tok * DIM;
    bf16* xb = xnb + (size_t)tok * DIM;
    float v[12];
    float s = 0.0f;
    #pragma unroll
    for (int i = 0; i < 6; ++i) {
        float2 xv = *(const float2*)&xr[lane * 2 + 128 * i];
        v[2 * i] = xv.x; v[2 * i + 1] = xv.y;
        s += xv.x + xv.y;
    }
    #pragma unroll
    for (int o = 32; o > 0; o >>= 1) s += __shfl_xor(s, o, 64);
    float mean = s * (1.0f / 768.0f);
    float sq = 0.0f;
    #pragma unroll
    for (int i = 0; i < 12; ++i) { float d = v[i] - mean; sq += d * d; }
    #pragma unroll
    for (int o = 32; o > 0; o >>= 1) sq += __shfl_xor(sq, o, 64);
    float rstd = rsqrtf(sq * (1.0f / 768.0f) + 1e-5f);

    float acc[6] = {0, 0, 0, 0, 0, 0};
    #pragma unroll
    for (int i = 0; i < 6; ++i) {
        int d0 = lane * 2 + 128 * i;
        float xn0 = (v[2 * i]     - mean) * rstd * lng[d0]     + lnb[d0];
        float xn1 = (v[2 * i + 1] - mean) * rstd * lng[d0 + 1] + lnb[d0 + 1];
        union { unsigned u; bf16 h[2]; } pk;
        pk.h[0] = __float2bfloat16(xn0);
        pk.h[1] = __float2bfloat16(xn1);
        *(unsigned*)&xb[d0] = pk.u;
        float4 a = *(const float4*)&srw[d0 * 4];
        float4 b = *(const float4*)&srw[d0 * 4 + 4];
        acc[0] += xn0 * a.x + xn1 * b.x;
        acc[1] += xn0 * a.y + xn1 * b.y;
        acc[2] += xn0 * a.z + xn1 * b.z;
        acc[3] += xn0 * a.w + xn1 * b.w;
        float4 sw = *(const float4*)&shw[d0 * 2];
        acc[4] += xn0 * sw.x + xn1 * sw.z;
        acc[5] += xn0 * sw.y + xn1 * sw.w;
    }
    #pragma unroll
    for (int j = 0; j < 6; ++j) {
        #pragma unroll
        for (int o = 32; o > 0; o >>= 1) acc[j] += __shfl_xor(acc[j], o, 64);
    }
    if (lane == 0) {
        float l[4];
        #pragma unroll
        for (int j = 0; j < 4; ++j) l[j] = acc[j] + srb[j];
        float m = fmaxf(fmaxf(l[0], l[1]), fmaxf(l[2], l[3]));
        float e[4], ssum = 0.0f;
        #pragma unroll
        for (int j = 0; j < 4; ++j) { e[j] = expf(l[j] - m); ssum += e[j]; }
        float inv = 1.0f / ssum;
        float p[4];
        #pragma unroll
        for (int j = 0; j < 4; ++j) p[j] = e[j] * inv;
        int i0 = 0;
        for (int j = 1; j < 4; ++j) if (p[j] > p[i0]) i0 = j;
        int i1 = -1;
        for (int j = 0; j < 4; ++j) {
            if (j == i0) continue;
            if (i1 < 0 || p[j] > p[i1]) i1 = j;
        }
        float sl0 = acc[4] + shb[0], sl1 = acc[5] + shb[1];
        float sm = fmaxf(sl0, sl1);
        float se0 = expf(sl0 - sm), se1 = expf(sl1 - sm);
        float sinv = 1.0f / (se0 + se1);
        float sp0 = se0 * sinv, sp1 = se1 * sinv;

        #pragma unroll
        for (int j = 0; j < 4; ++j) {
            spec_logits[tok * 4 + j] = l[j];
            spec_probs[tok * 4 + j]  = p[j];
        }
        topk_idx[tok * 2 + 0]   = (float)i0;
        topk_idx[tok * 2 + 1]   = (float)i1;
        topk_probs[tok * 2 + 0] = p[i0];
        topk_probs[tok * 2 + 1] = p[i1];
        sh_logits[tok * 2 + 0]  = sl0;
        sh_logits[tok * 2 + 1]  = sl1;
        sh_probs[tok * 2 + 0]   = sp0;
        sh_probs[tok * 2 + 1]   = sp1;
        float gg[6] = {0, 0, 0, 0, sp0, sp1};
        gg[i0] = p[i0];
        gg[i1] = p[i1];
        #pragma unroll
        for (int j = 0; j < 6; ++j) gates[tok * 6 + j] = gg[j];
        int c0 = i0 * NBKT + bucket;
        int pos0 = atomicAdd(&cnt2[c0], 1);
        tok2[c0 * BKTCAP + pos0]  = tok * 2 + 0;
        gate2[c0 * BKTCAP + pos0] = p[i0];
        int c1 = i1 * NBKT + bucket;
        int pos1 = atomicAdd(&cnt2[c1], 1);
        tok2[c1 * BKTCAP + pos1]  = tok * 2 + 1;
        gate2[c1 * BKTCAP + pos1] = p[i1];
    }
}

// ---------------------------------------------------------------- plan: bucket scan, 256-row padded compact
__global__ void plan_kernel(const int* __restrict__ cnt2, int* __restrict__ e_of_tile,
                            const int* __restrict__ tok2, const float* __restrict__ gate2,
                            int* __restrict__ slot_tok, float* __restrict__ slot_gate,
                            int* __restrict__ back) {
    __shared__ int sbase[4 * NBKT];
    __shared__ int offsE[5];
    __shared__ int etot[4];
    int tid = threadIdx.x, lane = tid & 63, wid = tid >> 6;
    int c = cnt2[wid * NBKT + lane];
    int inc = c;
    #pragma unroll
    for (int o = 1; o < 64; o <<= 1) {
        int tv = __shfl_up(inc, o, 64);
        if (lane >= o) inc += tv;
    }
    int exc = inc - c;
    if (lane == 63) etot[wid] = inc;
    __syncthreads();
    if (tid == 0) {
        int o = 0;
        for (int e = 0; e < 4; ++e) { offsE[e] = o; o += (etot[e] + 255) & ~255; }
        offsE[4] = o;
    }
    __syncthreads();
    sbase[tid] = offsE[wid] + exc;
    for (int idx = tid; idx < NTILE_MAX; idx += 256) {
        int s0 = idx * 256, e = -1;
        for (int j = 0; j < 4; ++j)
            if (s0 >= offsE[j] && s0 < offsE[j + 1]) e = j;
        e_of_tile[idx] = e;
    }
    __syncthreads();
    int bs = sbase[tid];
    int cc = cnt2[tid];
    for (int i = 0; i < cc; ++i) {
        int gs = bs + i;
        int tk = tok2[tid * BKTCAP + i];
        slot_tok[gs] = tk >> 1;
        slot_gate[gs] = gate2[tid * BKTCAP + i];
        back[tk] = gs;
    }
}

// ---------------------------------------------------------------- gather: pack spec-slot A rows into xg (aliased w/ spec_g)
__global__ void gather_kernel(const bf16* __restrict__ xnb, const int* __restrict__ slot_tok,
                              bf16* __restrict__ xg) {
    int idx = blockIdx.x * 256 + threadIdx.x;
    int slot = idx / 96;
    int c = (idx % 96) * 8;
    int tok = slot_tok[slot];
    *(short8v*)&xg[(size_t)slot * DIM + c] = *(const short8v*)&xnb[(size_t)tok * DIM + c];
}

// ================================================================ shared MFMA helpers
__device__ __forceinline__ int swz(int off) {
    return off ^ (((off >> 8) & 1) << 4) ^ (((off >> 9) & 1) << 5);
}

__device__ __forceinline__ void stage2(bf16* lds, int base_elems, int wid,
                                       const bf16* s0, const bf16* s1) {
    __builtin_amdgcn_global_load_lds(GPTR(s0), LDSPTR(lds + base_elems + wid * 512), 16, 0, 0);
    __builtin_amdgcn_global_load_lds(GPTR(s1), LDSPTR(lds + base_elems + 4096 + wid * 512), 16, 0, 0);
}

__device__ __forceinline__ void mfma16(const short8v a[4], const short8v b[4], f32x4 (*am)[4]) {
    #pragma unroll
    for (int i = 0; i < 4; ++i)
        #pragma unroll
        for (int j = 0; j < 4; ++j)
            am[i][j] = __builtin_amdgcn_mfma_f32_16x16x32_bf16(a[i], b[j], am[i][j], 0, 0, 0);
}

#define BARRIER() __builtin_amdgcn_s_barrier()
#define VMCNT4() asm volatile("s_waitcnt vmcnt(4)" ::: "memory")
#define VMCNT3() asm volatile("s_waitcnt vmcnt(3)" ::: "memory")
#define VMCNT0() asm volatile("s_waitcnt vmcnt(0)" ::: "memory")

// ================================================================ 256x256 8-phase core (gemm2, refcheck'd R8-R13)
__device__ __forceinline__ void read_a4(const bf16* lds, int buf, int ks, int wm, int mh,
                                        int lane, short8v a[4]) {
    const char* base = (const char*)lds + buf * 32768 + ks * 16384;
    #pragma unroll
    for (int i = 0; i < 4; ++i) {
        int off = (wm * 128 + mh * 64 + i * 16 + (lane & 15)) * 64 + ((lane >> 4) * 16);
        a[i] = *(const short8v*)(base + swz(off));
    }
}

__device__ __forceinline__ void read_b4(const bf16* lds, int buf, int ks, int wn,
                                        int lane, short8v b[4]) {
    const char* base = (const char*)lds + 65536 + buf * 32768 + ks * 16384;
    #pragma unroll
    for (int j = 0; j < 4; ++j) {
        int off = (wn * 64 + j * 16 + (lane & 15)) * 64 + ((lane >> 4) * 16);
        b[j] = *(const short8v*)(base + swz(off));
    }
}

template<int NT>
__device__ __forceinline__ void kloop8p(bf16* lds, const bf16* a0, const bf16* a1,
                                        const bf16* b0, const bf16* b1,
                                        int wm, int wn, int wid, int lane,
                                        f32x4 acc[8][4]) {
    stage2(lds, 0, wid, a0, a1);
    stage2(lds, 32768, wid, b0, b1);
    stage2(lds, 8192, wid, a0 + 32, a1 + 32);
    stage2(lds, 32768 + 8192, wid, b0 + 32, b1 + 32);
    VMCNT4();
    BARRIER();
    for (int t = 0; t < NT; ++t) {
        int buf = t & 1, nb = buf ^ 1;
        bool pre = (t + 1 < NT);
        short8v af[4], bfv[4];
        if (pre) stage2(lds, nb * 16384, wid, a0 + (t + 1) * 64, a1 + (t + 1) * 64);
        read_a4(lds, buf, 0, wm, 0, lane, af);
        read_b4(lds, buf, 0, wn, lane, bfv);
        BARRIER();
        __builtin_amdgcn_s_setprio(1);
        mfma16(af, bfv, &acc[0]);
        __builtin_amdgcn_s_setprio(0);
        BARRIER();
        if (pre) stage2(lds, 32768 + nb * 16384, wid, b0 + (t + 1) * 64, b1 + (t + 1) * 64);
        read_a4(lds, buf, 0, wm, 1, lane, af);
        BARRIER();
        __builtin_amdgcn_s_setprio(1);
        mfma16(af, bfv, &acc[4]);
        __builtin_amdgcn_s_setprio(0);
        if (pre) VMCNT4(); else VMCNT0();
        BARRIER();
        if (pre) stage2(lds, nb * 16384 + 8192, wid, a0 + (t + 1) * 64 + 32, a1 + (t + 1) * 64 + 32);
        read_a4(lds, buf, 1, wm, 0, lane, af);
        read_b4(lds, buf, 1, wn, lane, bfv);
        BARRIER();
        __builtin_amdgcn_s_setprio(1);
        mfma16(af, bfv, &acc[0]);
        __builtin_amdgcn_s_setprio(0);
        BARRIER();
        if (pre) stage2(lds, 32768 + nb * 16384 + 8192, wid, b0 + (t + 1) * 64 + 32, b1 + (t + 1) * 64 + 32);
        read_a4(lds, buf, 1, wm, 1, lane, af);
        BARRIER();
        __builtin_amdgcn_s_setprio(1);
        mfma16(af, bfv, &acc[4]);
        __builtin_amdgcn_s_setprio(0);
        if (pre) VMCNT4();
        BARRIER();
    }
}

// ================================================================ 128x256 2-phase core (gemm1, refcheck'd R13)
__device__ __forceinline__ void read_a4_128(const bf16* lds, int cur, int wm,
                                            int lane, short8v a[4]) {
    const char* base = (const char*)lds + cur * 8192;
    #pragma unroll
    for (int i = 0; i < 4; ++i) {
        int off = (wm * 64 + i * 16 + (lane & 15)) * 64 + ((lane >> 4) * 16);
        a[i] = *(const short8v*)(base + swz(off));
    }
}

__device__ __forceinline__ void read_b4_128(const bf16* lds, int cur, int wn,
                                            int lane, short8v b[4]) {
    const char* base = (const char*)lds + 16384 + cur * 16384;
    #pragma unroll
    for (int j = 0; j < 4; ++j) {
        int off = (wn * 64 + j * 16 + (lane & 15)) * 64 + ((lane >> 4) * 16);
        b[j] = *(const short8v*)(base + swz(off));
    }
}

template<int NS>
__device__ __forceinline__ void kloop2p(bf16* lds, const bf16* aA,
                                        const bf16* b0, const bf16* b1,
                                        int wm, int wn, int wid, int lane,
                                        f32x4 acc[4][4]) {
    __builtin_amdgcn_global_load_lds(GPTR(aA), LDSPTR(lds + wid * 512), 16, 0, 0);
    stage2(lds, 8192, wid, b0, b1);
    for (int s = 0; s < NS; ++s) {
        int cur = s & 1, nb = cur ^ 1;
        bool pre = (s + 1 < NS);
        if (pre) {
            __builtin_amdgcn_global_load_lds(GPTR(aA + (s + 1) * 32),
                                             LDSPTR(lds + nb * 4096 + wid * 512), 16, 0, 0);
            stage2(lds, 8192 + nb * 8192, wid, b0 + (s + 1) * 32, b1 + (s + 1) * 32);
        }
        if (pre) VMCNT3(); else VMCNT0();
        BARRIER();
        short8v av[4], bv[4];
        read_a4_128(lds, cur, wm, lane, av);
        read_b4_128(lds, cur, wn, lane, bv);
        __builtin_amdgcn_s_setprio(1);
        mfma16(av, bv, &acc[0]);
        __builtin_amdgcn_s_setprio(0);
        BARRIER();
    }
}

__device__ __forceinline__ float gelu_exact(float v) {
    return 0.5f * v * (1.0f + erff(v * 0.70710678118654752f));
}

// fast exact-GELU: A&S 7.1.26 erf (|err|<1.5e-7) + hw exp/rcp
__device__ __forceinline__ float gelu_fast(float x) {
    float z = 0.70710678118654752f * x;
    float az = fabsf(z);
    float t = __builtin_amdgcn_rcpf(1.0f + 0.3275911f * az);
    float poly = t * (0.254829592f + t * (-0.284496736f + t * (1.421413741f +
                 t * (-1.453152027f + t * 1.061405429f))));
    float erfv = 1.0f - poly * __expf(-az * az);
    erfv = (z < 0.0f) ? -erfv : erfv;
    return 0.5f * x * (1.0f + erfv);
}

// ---------------------------------------------------------------- GEMM1 2-phase 128x256 (refcheck'd R13)
__global__ __launch_bounds__(512, 4) void gemm1_2p(
    const bf16* __restrict__ xg, const bf16* __restrict__ xnb,
    const bf16* __restrict__ w1t,
    const float* __restrict__ spec_b1, const float* __restrict__ sh_b1,
    const int* __restrict__ e_of_tile,
    bf16* __restrict__ Hbuf, int y_base) {
    extern __shared__ bf16 lds[];
    int bx = blockIdx.x, by = blockIdx.y;
    int lt = by >> 1, half = by & 1;
    int y = y_base + lt;
    int tid = threadIdx.x, wid = tid >> 6, lane = tid & 63;
    int wm = wid >> 2, wn = wid & 3;
    int PA = tid;
    int LA = PA ^ ((PA >> 4) & 1) ^ (((PA >> 5) & 1) << 1);
    int ra = LA >> 2, ca = (LA & 3) * 8;
    int P0c = tid, P1c = 512 + tid;
    int L0 = P0c ^ ((P0c >> 4) & 1) ^ (((P0c >> 5) & 1) << 1);
    int L1 = P1c ^ ((P1c >> 4) & 1) ^ (((P1c >> 5) & 1) << 1);
    int rb0 = L0 >> 2, cb0 = (L0 & 3) * 8;
    int rb1 = L1 >> 2, cb1 = (L1 & 3) * 8;

    const bf16 *abase, *Bw;
    const float* bias;
    if (y < NTILE_MAX) {
        int e = e_of_tile[y];
        if (e < 0) return;
        abase = xg + (size_t)(y * 256 + half * 128) * DIM;
        Bw = w1t + (size_t)e * HID * DIM;
        bias = spec_b1 + (size_t)e * HID;
    } else {
        int ys = y - NTILE_MAX;
        int z = ys / NSDT, ry = ys % NSDT;
        abase = xnb + (size_t)(ry * 256 + half * 128) * DIM;
        Bw = w1t + (size_t)(4 + z) * HID * DIM;
        bias = sh_b1 + (size_t)z * HID;
    }
    const bf16* aA = abase + (size_t)ra * DIM + ca;
    const bf16* b0 = Bw + (size_t)(bx * 256 + rb0) * DIM + cb0;
    const bf16* b1 = Bw + (size_t)(bx * 256 + rb1) * DIM + cb1;

    f32x4 acc[4][4] = {};
    kloop2p<DIM / 32>(lds, aA, b0, b1, wm, wn, wid, lane, acc);

    bf16* hb = Hbuf + (size_t)(lt * 256 + half * 128) * HID;
    int fr = lane & 15, fq = lane >> 4;
    int cb = bx * 256 + wn * 64;
    #pragma unroll
    for (int j = 0; j < 4; ++j) {
        int col = cb + j * 16 + fr;
        float bv = bias[col];
        #pragma unroll
        for (int i = 0; i < 4; ++i) {
            #pragma unroll
            for (int rr = 0; rr < 4; ++rr) {
                int row = wm * 64 + i * 16 + fq * 4 + rr;
                hb[(size_t)row * HID + col] = __float2bfloat16(gelu_fast(acc[i][j][rr] + bv));
            }
        }
    }
}

// ---------------------------------------------------------------- GEMM2 8-phase 256x256 (restored from R13)
__global__ __launch_bounds__(512, 2) void gemm2_8p(
    const bf16* __restrict__ Hbuf, const bf16* __restrict__ w2t,
    const float* __restrict__ spec_b2, const float* __restrict__ sh_b2,
    const int* __restrict__ e_of_tile, const float* __restrict__ slot_gate,
    const float* __restrict__ sh_probs,
    bf16* __restrict__ spec_g, bf16* __restrict__ shg, int y_base) {
    extern __shared__ bf16 lds[];
    int bx = blockIdx.x, by = blockIdx.y;
    int y = by + y_base;
    int tid = threadIdx.x, wid = tid >> 6, lane = tid & 63;
    int wm = wid >> 2, wn = wid & 3;
    int P0c = tid, P1c = 512 + tid;
    int L0 = P0c ^ ((P0c >> 4) & 1) ^ (((P0c >> 5) & 1) << 1);
    int L1 = P1c ^ ((P1c >> 4) & 1) ^ (((P1c >> 5) & 1) << 1);
    int r0 = L0 >> 2, c0 = (L0 & 3) * 8;
    int r1 = L1 >> 2, c1 = (L1 & 3) * 8;

    const bf16 *Bw;
    const float* bias;
    bf16* obase;
    bool grouped = (y < NTILE_MAX);
    int z = 0, ry = 0;
    if (grouped) {
        int e = e_of_tile[y];
        if (e < 0) return;
        Bw = w2t + (size_t)e * DIM * HID;
        bias = spec_b2 + (size_t)e * DIM;
        obase = spec_g + (size_t)y * 256 * DIM;
    } else {
        int ys = y - NTILE_MAX;
        z = ys / NSDT; ry = ys % NSDT;
        Bw = w2t + (size_t)(4 + z) * DIM * HID;
        bias = sh_b2 + (size_t)z * DIM;
        obase = shg + (size_t)(z * NTOK + ry * 256) * DIM;
    }
    const bf16* Ah = Hbuf + (size_t)by * 256 * HID;
    const bf16* a0 = Ah + (size_t)r0 * HID + c0;
    const bf16* a1 = Ah + (size_t)r1 * HID + c1;
    const bf16* b0 = Bw + (size_t)(bx * 256 + r0) * HID + c0;
    const bf16* b1 = Bw + (size_t)(bx * 256 + r1) * HID + c1;

    f32x4 acc[8][4] = {};
    kloop8p<HID / 64>(lds, a0, a1, b0, b1, wm, wn, wid, lane, acc);

    int fr = lane & 15, fq = lane >> 4;
    int cb = bx * 256 + wn * 64;
    #pragma unroll
    for (int j = 0; j < 4; ++j) {
        int col = cb + j * 16 + fr;
        float bv = bias[col];
        #pragma unroll
        for (int ii = 0; ii < 8; ++ii) {
            #pragma unroll
            for (int rr = 0; rr < 4; ++rr) {
                int row = wm * 128 + (ii >> 2) * 64 + (ii & 3) * 16 + fq * 4 + rr;
                float g = grouped ? slot_gate[y * 256 + row]
                                  : sh_probs[(size_t)(ry * 256 + row) * 2 + z];
                obase[(size_t)row * DIM + col] = __float2bfloat16(g * (acc[ii][j][rr] + bv));
            }
        }
    }
}

// ---------------------------------------------------------------- plan-B dense fallback (128^2 m97, known-good)
__device__ __forceinline__ void stage_tile(const bf16* __restrict__ g, int ldg,
                                           bf16* lds, int tid) {
    int wave = tid >> 6, lane = tid & 63;
    #pragma unroll
    for (int q = 0; q < 2; ++q) {
        int chunk = wave * 2 + q;
        int row = chunk * 16 + (lane >> 2);
        int col = (lane & 3) * 8;
        __builtin_amdgcn_global_load_lds(GPTR(g + (size_t)row * ldg + col),
                                         LDSPTR(lds + chunk * 512), 16, 0, 0);
    }
}

__device__ __forceinline__ void mfma_step(const bf16* As, const bf16* Bs,
                                          int wr, int wc, int fr, int fq, f32x4 acc[4][4]) {
    short8v a[4], b[4];
    #pragma unroll
    for (int i = 0; i < 4; ++i) {
        a[i] = *(const short8v*)&As[(wr * 64 + i * 16 + fr) * 32 + fq * 8];
        b[i] = *(const short8v*)&Bs[(wc * 64 + i * 16 + fr) * 32 + fq * 8];
    }
    #pragma unroll
    for (int i = 0; i < 4; ++i)
        #pragma unroll
        for (int j = 0; j < 4; ++j)
            acc[i][j] = __builtin_amdgcn_mfma_f32_16x16x32_bf16(a[i], b[j], acc[i][j], 0, 0, 0);
}

__global__ __launch_bounds__(256) void gemm1_dense(
    const bf16* __restrict__ A, const bf16* __restrict__ BT,
    const float* __restrict__ bias, bf16* __restrict__ H) {
    __shared__ bf16 As[128 * 32];
    __shared__ bf16 Bs[128 * 32];
    int tid = threadIdx.x;
    int wid = tid >> 6, lane = tid & 63;
    int wr = wid >> 1, wc = wid & 1;
    int fr = lane & 15, fq = lane >> 4;
    const bf16* Ag = A + (size_t)(blockIdx.y * 128) * DIM;
    const bf16* Bg = BT + (size_t)(blockIdx.x * 128) * DIM;
    f32x4 acc[4][4] = {};
    for (int k0 = 0; k0 < DIM; k0 += 32) {
        stage_tile(Ag + k0, DIM, As, tid);
        stage_tile(Bg + k0, DIM, Bs, tid);
        __syncthreads();
        mfma_step(As, Bs, wr, wc, fr, fq, acc);
        __syncthreads();
    }
    int rbase = blockIdx.y * 128 + wr * 64;
    int cbase = blockIdx.x * 128 + wc * 64;
    #pragma unroll
    for (int j = 0; j < 4; ++j) {
        int col = cbase + j * 16 + fr;
        float bv = bias[col];
        #pragma unroll
        for (int i = 0; i < 4; ++i)
            #pragma unroll
            for (int r = 0; r < 4; ++r) {
                int row = rbase + i * 16 + fq * 4 + r;
                H[(size_t)row * HID + col] = __float2bfloat16(gelu_exact(acc[i][j][r] + bv));
            }
    }
}

__global__ __launch_bounds__(256) void gemm2_dense_out(
    const bf16* __restrict__ A, const bf16* __restrict__ BT,
    const float* __restrict__ bias, const float* __restrict__ gates,
    float* __restrict__ out, int gidx, int accum) {
    __shared__ bf16 As[128 * 32];
    __shared__ bf16 Bs[128 * 32];
    int tid = threadIdx.x;
    int wid = tid >> 6, lane = tid & 63;
    int wr = wid >> 1, wc = wid & 1;
    int fr = lane & 15, fq = lane >> 4;
    const bf16* Ag = A + (size_t)(blockIdx.y * 128) * HID;
    const bf16* Bg = BT + (size_t)(blockIdx.x * 128) * HID;
    f32x4 acc[4][4] = {};
    for (int k0 = 0; k0 < HID; k0 += 32) {
        stage_tile(Ag + k0, HID, As, tid);
        stage_tile(Bg + k0, HID, Bs, tid);
        __syncthreads();
        mfma_step(As, Bs, wr, wc, fr, fq, acc);
        __syncthreads();
    }
    int rbase = blockIdx.y * 128 + wr * 64;
    int cbase = blockIdx.x * 128 + wc * 64;
    #pragma unroll
    for (int j = 0; j < 4; ++j) {
        int col = cbase + j * 16 + fr;
        float bv = bias[col];
        #pragma unroll
        for (int i = 0; i < 4; ++i)
            #pragma unroll
            for (int r = 0; r < 4; ++r) {
                int row = rbase + i * 16 + fq * 4 + r;
                float g = gates[(size_t)row * 6 + gidx];
                float v = g * (acc[i][j][r] + bv);
                size_t idx = (size_t)row * DIM + col;
                out[idx] = accum ? out[idx] + v : v;
            }
    }
}

// ---------------------------------------------------------------- combine
__global__ void combine_kernel(const bf16* __restrict__ spec_g, const bf16* __restrict__ shg,
                               const int* __restrict__ back, float* __restrict__ out) {
    int idx = blockIdx.x * 256 + threadIdx.x;
    int tok = idx / 96;
    int c = (idx % 96) * 8;
    int b0 = back[2 * tok], b1 = back[2 * tok + 1];
    short8v q0 = *(const short8v*)&spec_g[(size_t)b0 * DIM + c];
    short8v q1 = *(const short8v*)&spec_g[(size_t)b1 * DIM + c];
    short8v s0 = *(const short8v*)&shg[(size_t)tok * DIM + c];
    short8v s1 = *(const short8v*)&shg[(size_t)(NTOK + tok) * DIM + c];
    float o[8];
    #pragma unroll
    for (int k = 0; k < 8; ++k) {
        float f0 = __uint_as_float((unsigned)(unsigned short)q0[k] << 16);
        float f1 = __uint_as_float((unsigned)(unsigned short)q1[k] << 16);
        float f2 = __uint_as_float((unsigned)(unsigned short)s0[k] << 16);
        float f3 = __uint_as_float((unsigned)(unsigned short)s1[k] << 16);
        o[k] = f0 + f1 + f2 + f3;
    }
    float* op = out + (size_t)tok * DIM + c;
    *(float4*)(op)     = *(const float4*)(o);
    *(float4*)(op + 4) = *(const float4*)(o + 4);
}

// ---------------------------------------------------------------- launch
static inline size_t align256(size_t x) { return (x + 255) & ~(size_t)255; }

extern "C" void kernel_launch(void* const* d_in, const int* in_sizes, int n_in,
                              void* d_out, int out_size, void* d_ws, size_t ws_size,
                              hipStream_t stream) {
    const float* x      = (const float*)d_in[0];
    const float* gamma  = (const float*)d_in[1];
    const float* beta   = (const float*)d_in[2];
    const float* srw    = (const float*)d_in[3];
    const float* srb    = (const float*)d_in[4];
    const float* spec_w1 = (const float*)d_in[5];
    const float* spec_b1 = (const float*)d_in[6];
    const float* spec_w2 = (const float*)d_in[7];
    const float* spec_b2 = (const float*)d_in[8];
    const float* shw    = (const float*)d_in[9];
    const float* shb    = (const float*)d_in[10];
    const float* sh_w1  = (const float*)d_in[11];
    const float* sh_b1  = (const float*)d_in[12];
    const float* sh_w2  = (const float*)d_in[13];
    const float* sh_b2  = (const float*)d_in[14];

    char* p = (char*)d_ws;
    size_t off = 0;
    bf16* xnb = (bf16*)(p + off);       off = align256(off + (size_t)NTOK * DIM * 2);
    bf16* w1t = (bf16*)(p + off);       off = align256(off + (size_t)6 * HID * DIM * 2);
    bf16* w2t = (bf16*)(p + off);       off = align256(off + (size_t)6 * DIM * HID * 2);
    int*  cnt2 = (int*)(p + off);       off = align256(off + (size_t)4 * NBKT * 4);
    float* gates = (float*)(p + off);   off = align256(off + (size_t)NTOK * 6 * 4);
    int*  tok2 = (int*)(p + off);       off = align256(off + (size_t)4 * NBKT * BKTCAP * 4);
    float* gate2 = (float*)(p + off);   off = align256(off + (size_t)4 * NBKT * BKTCAP * 4);
    int*  slot_tok = (int*)(p + off);   off = align256(off + (size_t)NSLOT_MAX * 4);
    float* slot_gate = (float*)(p + off); off = align256(off + (size_t)NSLOT_MAX * 4);
    int*  back = (int*)(p + off);       off = align256(off + (size_t)2 * NTOK * 4);
    int*  e_of_tile = (int*)(p + off);  off = align256(off + (size_t)NTILE_MAX * 4);
    bf16* spec_g = (bf16*)(p + off);    off = align256(off + (size_t)NSLOT_MAX * DIM * 2);
    bf16* shg   = (bf16*)(p + off);     off = align256(off + (size_t)2 * NTOK * DIM * 2);
    size_t fixed_end = off;
    bf16* Hbuf = (bf16*)(p + fixed_end);
    bf16* xg = spec_g;   // aliased: gather-write -> g1 read -> g2 write -> combine read

    const size_t tile_bytes = (size_t)256 * HID * 2;
    size_t avail = (ws_size > fixed_end) ? (ws_size - fixed_end) : 0;
    int tcap = (int)(avail / tile_bytes);
    if (tcap > NVT) tcap = NVT;

    float* out         = (float*)d_out;
    float* spec_logits = out + (size_t)NTOK * DIM;
    float* spec_probs  = spec_logits + (size_t)NTOK * 4;
    float* topk_idx    = spec_probs  + (size_t)NTOK * 4;
    float* topk_probs  = topk_idx    + (size_t)NTOK * 2;
    float* sh_logits   = topk_probs  + (size_t)NTOK * 2;
    float* sh_probs    = sh_logits   + (size_t)NTOK * 2;

    hipMemsetAsync(cnt2, 0, (size_t)4 * NBKT * 4, stream);
    prep_kernel<<<NCONVB + NTOK / 4, 256, 0, stream>>>(
        spec_w1, sh_w1, spec_w2, sh_w2, w1t, w2t, slot_tok, slot_gate,
        x, gamma, beta, srw, srb, shw, shb, xnb,
        spec_logits, spec_probs, topk_idx, topk_probs, sh_logits, sh_probs,
        gates, cnt2, tok2, gate2);

    if (tcap >= 8) {
        plan_kernel<<<1, 256, 0, stream>>>(cnt2, e_of_tile, tok2, gate2,
                                           slot_tok, slot_gate, back);
        gather_kernel<<<NSLOT_MAX * 96 / 256, 256, 0, stream>>>(xnb, slot_tok, xg);
        int csz = tcap >= 67 ? (NVT + 2) / 3 : (tcap < 64 ? tcap : 64);
        if (csz > tcap) csz = tcap;
        for (int c0 = 0; c0 < NVT; c0 += csz) {
            int n = NVT - c0 < csz ? NVT - c0 : csz;
            gemm1_2p<<<dim3(HID / 256, 2 * n), 512, LDSB1, stream>>>(
                xg, xnb, w1t, spec_b1, sh_b1, e_of_tile, Hbuf, c0);
            gemm2_8p<<<dim3(DIM / 256, n), 512, LDSB, stream>>>(
                Hbuf, w2t, spec_b2, sh_b2, e_of_tile, slot_gate, sh_probs,
                spec_g, shg, c0);
        }
        combine_kernel<<<NTOK * 96 / 256, 256, 0, stream>>>(spec_g, shg, back, out);
    } else {
        // plan B: dense 6-expert loop (reuses spec_g/shg region as H)
        bf16* HB = spec_g;
        for (int e = 0; e < 6; ++e) {
            const bf16* w1p = w1t + (size_t)e * HID * DIM;
            const bf16* w2p = w2t + (size_t)e * DIM * HID;
            const float* b1p = (e < 4) ? spec_b1 + (size_t)e * HID : sh_b1 + (size_t)(e - 4) * HID;
            const float* b2p = (e < 4) ? spec_b2 + (size_t)e * DIM : sh_b2 + (size_t)(e - 4) * DIM;
            gemm1_dense<<<dim3(HID / 128, NTOK / 128), 256, 0, stream>>>(xnb, w1p, b1p, HB);
            gemm2_dense_out<<<dim3(DIM / 128, NTOK / 128), 256, 0, stream>>>(
                HB, w2p, b2p, gates, out, e, e > 0);
        }
    }
}

// Round 16
// 784.267 us; speedup vs baseline: 1.0850x; 1.0679x over previous
//
#include <hip/hip_runtime.h>
#include <hip/hip_bf16.h>
#include <math.h>

#define NTOK 12544
#define DIM 768
#define HID 3072
#define NTILE_MAX 102               // spec 256-row tiles
#define NSLOT_MAX (NTILE_MAX * 256) // 26112 slots
#define NSDT 49                     // NTOK/256 dense row tiles per shared expert
#define NVT (NTILE_MAX + 2 * NSDT)  // 200 virtual 256-row tiles
#define NBKT 64
#define BKTCAP 256
#define LDSB 131072                 // gemm2 (256x256 8-phase)
#define LDSB1 49152                 // gemm1 (128x256 2-phase)
#define NCONVB 6912                 // conv blocks in prep_kernel (576*12)

typedef __hip_bfloat16 bf16;
typedef __attribute__((ext_vector_type(8))) short short8v;
typedef __attribute__((ext_vector_type(4))) float f32x4;

#define GPTR(p)  ((const __attribute__((address_space(1))) void*)(p))
#define LDSPTR(p) ((__attribute__((address_space(3))) void*)(p))

// ---------------------------------------------------------------- prep: conv (bid<NCONVB) + router_ln (else)
__global__ __launch_bounds__(256) void prep_kernel(
    const float* __restrict__ spec_w1, const float* __restrict__ sh_w1,
    const float* __restrict__ spec_w2, const float* __restrict__ sh_w2,
    bf16* __restrict__ w1t, bf16* __restrict__ w2t,
    int* __restrict__ slot_tok, float* __restrict__ slot_gate,
    const float* __restrict__ x,
    const float* __restrict__ lng, const float* __restrict__ lnb,
    const float* __restrict__ srw, const float* __restrict__ srb,
    const float* __restrict__ shw, const float* __restrict__ shb,
    bf16* __restrict__ xnb,
    float* __restrict__ spec_logits, float* __restrict__ spec_probs,
    float* __restrict__ topk_idx, float* __restrict__ topk_probs,
    float* __restrict__ sh_logits, float* __restrict__ sh_probs,
    float* __restrict__ gates,
    int* __restrict__ cnt2, int* __restrict__ tok2, float* __restrict__ gate2) {
    __shared__ float tile[64][65];
    int bid = blockIdx.x;
    int t = threadIdx.x;
    if (bid < NCONVB) {
        int z = bid / 576, ti = bid % 576;
        if (z == 0 && ti < NTILE_MAX) {
            int s = ti * 256 + t;
            slot_tok[s] = 0; slot_gate[s] = 0.0f;
        }
        const float* src; bf16* dst; int R, C, tr, tc;
        if (z < 6) {
            R = DIM; C = HID;
            src = (z < 4) ? spec_w1 + (size_t)z * R * C : sh_w1 + (size_t)(z - 4) * R * C;
            dst = w1t + (size_t)z * R * C;
            tr = ti % 12; tc = ti / 12;
        } else {
            int e = z - 6;
            R = HID; C = DIM;
            src = (e < 4) ? spec_w2 + (size_t)e * R * C : sh_w2 + (size_t)(e - 4) * R * C;
            dst = w2t + (size_t)e * R * C;
            tr = ti % 48; tc = ti / 48;
        }
        int r0 = tr * 64, c0 = tc * 64;
        int lr = t >> 4, lc = (t & 15) * 4;
        #pragma unroll
        for (int ii = 0; ii < 4; ++ii) {
            float4 v = *(const float4*)&src[(size_t)(r0 + lr + 16 * ii) * C + c0 + lc];
            tile[lc + 0][lr + 16 * ii] = v.x;
            tile[lc + 1][lr + 16 * ii] = v.y;
            tile[lc + 2][lr + 16 * ii] = v.z;
            tile[lc + 3][lr + 16 * ii] = v.w;
        }
        __syncthreads();
        int oc = t >> 4, orr = (t & 15) * 4;
        #pragma unroll
        for (int ii = 0; ii < 4; ++ii) {
            union { ushort4 u4; bf16 h[4]; } pk;
            #pragma unroll
            for (int k = 0; k < 4; ++k)
                pk.h[k] = __float2bfloat16(tile[oc + 16 * ii][orr + k]);
            *(ushort4*)&dst[(size_t)(c0 + oc + 16 * ii) * R + r0 + orr] = pk.u4;
        }
        return;
    }
    int rid = bid - NCONVB;
    int tok = rid * 4 + (t >> 6);
    int bucket = rid & (NBKT - 1);
    int lane = t & 63;
    const float* xr = x + (size_t)tok * DIM;
    bf16* xb = xnb + (size_t)tok * DIM;
    float v[12];
    float s = 0.0f;
    #pragma unroll
    for (int i = 0; i < 6; ++i) {
        float2 xv = *(const float2*)&xr[lane * 2 + 128 * i];
        v[2 * i] = xv.x; v[2 * i + 1] = xv.y;
        s += xv.x + xv.y;
    }
    #pragma unroll
    for (int o = 32; o > 0; o >>= 1) s += __shfl_xor(s, o, 64);
    float mean = s * (1.0f / 768.0f);
    float sq = 0.0f;
    #pragma unroll
    for (int i = 0; i < 12; ++i) { float d = v[i] - mean; sq += d * d; }
    #pragma unroll
    for (int o = 32; o > 0; o >>= 1) sq += __shfl_xor(sq, o, 64);
    float rstd = rsqrtf(sq * (1.0f / 768.0f) + 1e-5f);

    float acc[6] = {0, 0, 0, 0, 0, 0};
    #pragma unroll
    for (int i = 0; i < 6; ++i) {
        int d0 = lane * 2 + 128 * i;
        float xn0 = (v[2 * i]     - mean) * rstd * lng[d0]     + lnb[d0];
        float xn1 = (v[2 * i + 1] - mean) * rstd * lng[d0 + 1] + lnb[d0 + 1];
        union { unsigned u; bf16 h[2]; } pk;
        pk.h[0] = __float2bfloat16(xn0);
        pk.h[1] = __float2bfloat16(xn1);
        *(unsigned*)&xb[d0] = pk.u;
        float4 a = *(const float4*)&srw[d0 * 4];
        float4 b = *(const float4*)&srw[d0 * 4 + 4];
        acc[0] += xn0 * a.x + xn1 * b.x;
        acc[1] += xn0 * a.y + xn1 * b.y;
        acc[2] += xn0 * a.z + xn1 * b.z;
        acc[3] += xn0 * a.w + xn1 * b.w;
        float4 sw = *(const float4*)&shw[d0 * 2];
        acc[4] += xn0 * sw.x + xn1 * sw.z;
        acc[5] += xn0 * sw.y + xn1 * sw.w;
    }
    #pragma unroll
    for (int j = 0; j < 6; ++j) {
        #pragma unroll
        for (int o = 32; o > 0; o >>= 1) acc[j] += __shfl_xor(acc[j], o, 64);
    }
    if (lane == 0) {
        float l[4];
        #pragma unroll
        for (int j = 0; j < 4; ++j) l[j] = acc[j] + srb[j];
        float m = fmaxf(fmaxf(l[0], l[1]), fmaxf(l[2], l[3]));
        float e[4], ssum = 0.0f;
        #pragma unroll
        for (int j = 0; j < 4; ++j) { e[j] = expf(l[j] - m); ssum += e[j]; }
        float inv = 1.0f / ssum;
        float p[4];
        #pragma unroll
        for (int j = 0; j < 4; ++j) p[j] = e[j] * inv;
        int i0 = 0;
        for (int j = 1; j < 4; ++j) if (p[j] > p[i0]) i0 = j;
        int i1 = -1;
        for (int j = 0; j < 4; ++j) {
            if (j == i0) continue;
            if (i1 < 0 || p[j] > p[i1]) i1 = j;
        }
        float sl0 = acc[4] + shb[0], sl1 = acc[5] + shb[1];
        float sm = fmaxf(sl0, sl1);
        float se0 = expf(sl0 - sm), se1 = expf(sl1 - sm);
        float sinv = 1.0f / (se0 + se1);
        float sp0 = se0 * sinv, sp1 = se1 * sinv;

        #pragma unroll
        for (int j = 0; j < 4; ++j) {
            spec_logits[tok * 4 + j] = l[j];
            spec_probs[tok * 4 + j]  = p[j];
        }
        topk_idx[tok * 2 + 0]   = (float)i0;
        topk_idx[tok * 2 + 1]   = (float)i1;
        topk_probs[tok * 2 + 0] = p[i0];
        topk_probs[tok * 2 + 1] = p[i1];
        sh_logits[tok * 2 + 0]  = sl0;
        sh_logits[tok * 2 + 1]  = sl1;
        sh_probs[tok * 2 + 0]   = sp0;
        sh_probs[tok * 2 + 1]   = sp1;
        float gg[6] = {0, 0, 0, 0, sp0, sp1};
        gg[i0] = p[i0];
        gg[i1] = p[i1];
        #pragma unroll
        for (int j = 0; j < 6; ++j) gates[tok * 6 + j] = gg[j];
        int c0 = i0 * NBKT + bucket;
        int pos0 = atomicAdd(&cnt2[c0], 1);
        tok2[c0 * BKTCAP + pos0]  = tok * 2 + 0;
        gate2[c0 * BKTCAP + pos0] = p[i0];
        int c1 = i1 * NBKT + bucket;
        int pos1 = atomicAdd(&cnt2[c1], 1);
        tok2[c1 * BKTCAP + pos1]  = tok * 2 + 1;
        gate2[c1 * BKTCAP + pos1] = p[i1];
    }
}

// ---------------------------------------------------------------- plan: bucket scan, 256-row padded compact
__global__ void plan_kernel(const int* __restrict__ cnt2, int* __restrict__ e_of_tile,
                            const int* __restrict__ tok2, const float* __restrict__ gate2,
                            int* __restrict__ slot_tok, float* __restrict__ slot_gate,
                            int* __restrict__ back) {
    __shared__ int sbase[4 * NBKT];
    __shared__ int offsE[5];
    __shared__ int etot[4];
    int tid = threadIdx.x, lane = tid & 63, wid = tid >> 6;
    int c = cnt2[wid * NBKT + lane];
    int inc = c;
    #pragma unroll
    for (int o = 1; o < 64; o <<= 1) {
        int tv = __shfl_up(inc, o, 64);
        if (lane >= o) inc += tv;
    }
    int exc = inc - c;
    if (lane == 63) etot[wid] = inc;
    __syncthreads();
    if (tid == 0) {
        int o = 0;
        for (int e = 0; e < 4; ++e) { offsE[e] = o; o += (etot[e] + 255) & ~255; }
        offsE[4] = o;
    }
    __syncthreads();
    sbase[tid] = offsE[wid] + exc;
    for (int idx = tid; idx < NTILE_MAX; idx += 256) {
        int s0 = idx * 256, e = -1;
        for (int j = 0; j < 4; ++j)
            if (s0 >= offsE[j] && s0 < offsE[j + 1]) e = j;
        e_of_tile[idx] = e;
    }
    __syncthreads();
    int bs = sbase[tid];
    int cc = cnt2[tid];
    for (int i = 0; i < cc; ++i) {
        int gs = bs + i;
        int tk = tok2[tid * BKTCAP + i];
        slot_tok[gs] = tk >> 1;
        slot_gate[gs] = gate2[tid * BKTCAP + i];
        back[tk] = gs;
    }
}

// ---------------------------------------------------------------- gather: pack spec-slot A rows into xg (aliased w/ spec_g)
__global__ void gather_kernel(const bf16* __restrict__ xnb, const int* __restrict__ slot_tok,
                              bf16* __restrict__ xg) {
    int idx = blockIdx.x * 256 + threadIdx.x;
    int slot = idx / 96;
    int c = (idx % 96) * 8;
    int tok = slot_tok[slot];
    *(short8v*)&xg[(size_t)slot * DIM + c] = *(const short8v*)&xnb[(size_t)tok * DIM + c];
}

// ================================================================ shared MFMA helpers
__device__ __forceinline__ int swz(int off) {
    return off ^ (((off >> 8) & 1) << 4) ^ (((off >> 9) & 1) << 5);
}

__device__ __forceinline__ void stage2(bf16* lds, int base_elems, int wid,
                                       const bf16* s0, const bf16* s1) {
    __builtin_amdgcn_global_load_lds(GPTR(s0), LDSPTR(lds + base_elems + wid * 512), 16, 0, 0);
    __builtin_amdgcn_global_load_lds(GPTR(s1), LDSPTR(lds + base_elems + 4096 + wid * 512), 16, 0, 0);
}

__device__ __forceinline__ void mfma16(const short8v a[4], const short8v b[4], f32x4 (*am)[4]) {
    #pragma unroll
    for (int i = 0; i < 4; ++i)
        #pragma unroll
        for (int j = 0; j < 4; ++j)
            am[i][j] = __builtin_amdgcn_mfma_f32_16x16x32_bf16(a[i], b[j], am[i][j], 0, 0, 0);
}

#define BARRIER() __builtin_amdgcn_s_barrier()
#define VMCNT4() asm volatile("s_waitcnt vmcnt(4)" ::: "memory")
#define VMCNT3() asm volatile("s_waitcnt vmcnt(3)" ::: "memory")
#define VMCNT0() asm volatile("s_waitcnt vmcnt(0)" ::: "memory")

// ================================================================ 256x256 8-phase core (gemm2, refcheck'd R8-R15)
__device__ __forceinline__ void read_a4(const bf16* lds, int buf, int ks, int wm, int mh,
                                        int lane, short8v a[4]) {
    const char* base = (const char*)lds + buf * 32768 + ks * 16384;
    #pragma unroll
    for (int i = 0; i < 4; ++i) {
        int off = (wm * 128 + mh * 64 + i * 16 + (lane & 15)) * 64 + ((lane >> 4) * 16);
        a[i] = *(const short8v*)(base + swz(off));
    }
}

__device__ __forceinline__ void read_b4(const bf16* lds, int buf, int ks, int wn,
                                        int lane, short8v b[4]) {
    const char* base = (const char*)lds + 65536 + buf * 32768 + ks * 16384;
    #pragma unroll
    for (int j = 0; j < 4; ++j) {
        int off = (wn * 64 + j * 16 + (lane & 15)) * 64 + ((lane >> 4) * 16);
        b[j] = *(const short8v*)(base + swz(off));
    }
}

template<int NT>
__device__ __forceinline__ void kloop8p(bf16* lds, const bf16* a0, const bf16* a1,
                                        const bf16* b0, const bf16* b1,
                                        int wm, int wn, int wid, int lane,
                                        f32x4 acc[8][4]) {
    stage2(lds, 0, wid, a0, a1);
    stage2(lds, 32768, wid, b0, b1);
    stage2(lds, 8192, wid, a0 + 32, a1 + 32);
    stage2(lds, 32768 + 8192, wid, b0 + 32, b1 + 32);
    VMCNT4();
    BARRIER();
    for (int t = 0; t < NT; ++t) {
        int buf = t & 1, nb = buf ^ 1;
        bool pre = (t + 1 < NT);
        short8v af[4], bfv[4];
        if (pre) stage2(lds, nb * 16384, wid, a0 + (t + 1) * 64, a1 + (t + 1) * 64);
        read_a4(lds, buf, 0, wm, 0, lane, af);
        read_b4(lds, buf, 0, wn, lane, bfv);
        BARRIER();
        __builtin_amdgcn_s_setprio(1);
        mfma16(af, bfv, &acc[0]);
        __builtin_amdgcn_s_setprio(0);
        BARRIER();
        if (pre) stage2(lds, 32768 + nb * 16384, wid, b0 + (t + 1) * 64, b1 + (t + 1) * 64);
        read_a4(lds, buf, 0, wm, 1, lane, af);
        BARRIER();
        __builtin_amdgcn_s_setprio(1);
        mfma16(af, bfv, &acc[4]);
        __builtin_amdgcn_s_setprio(0);
        if (pre) VMCNT4(); else VMCNT0();
        BARRIER();
        if (pre) stage2(lds, nb * 16384 + 8192, wid, a0 + (t + 1) * 64 + 32, a1 + (t + 1) * 64 + 32);
        read_a4(lds, buf, 1, wm, 0, lane, af);
        read_b4(lds, buf, 1, wn, lane, bfv);
        BARRIER();
        __builtin_amdgcn_s_setprio(1);
        mfma16(af, bfv, &acc[0]);
        __builtin_amdgcn_s_setprio(0);
        BARRIER();
        if (pre) stage2(lds, 32768 + nb * 16384 + 8192, wid, b0 + (t + 1) * 64 + 32, b1 + (t + 1) * 64 + 32);
        read_a4(lds, buf, 1, wm, 1, lane, af);
        BARRIER();
        __builtin_amdgcn_s_setprio(1);
        mfma16(af, bfv, &acc[4]);
        __builtin_amdgcn_s_setprio(0);
        if (pre) VMCNT4();
        BARRIER();
    }
}

// ================================================================ 128x256 2-phase core (gemm1, refcheck'd R13)
__device__ __forceinline__ void read_a4_128(const bf16* lds, int cur, int wm,
                                            int lane, short8v a[4]) {
    const char* base = (const char*)lds + cur * 8192;
    #pragma unroll
    for (int i = 0; i < 4; ++i) {
        int off = (wm * 64 + i * 16 + (lane & 15)) * 64 + ((lane >> 4) * 16);
        a[i] = *(const short8v*)(base + swz(off));
    }
}

__device__ __forceinline__ void read_b4_128(const bf16* lds, int cur, int wn,
                                            int lane, short8v b[4]) {
    const char* base = (const char*)lds + 16384 + cur * 16384;
    #pragma unroll
    for (int j = 0; j < 4; ++j) {
        int off = (wn * 64 + j * 16 + (lane & 15)) * 64 + ((lane >> 4) * 16);
        b[j] = *(const short8v*)(base + swz(off));
    }
}

template<int NS>
__device__ __forceinline__ void kloop2p(bf16* lds, const bf16* aA,
                                        const bf16* b0, const bf16* b1,
                                        int wm, int wn, int wid, int lane,
                                        f32x4 acc[4][4]) {
    __builtin_amdgcn_global_load_lds(GPTR(aA), LDSPTR(lds + wid * 512), 16, 0, 0);
    stage2(lds, 8192, wid, b0, b1);
    for (int s = 0; s < NS; ++s) {
        int cur = s & 1, nb = cur ^ 1;
        bool pre = (s + 1 < NS);
        if (pre) {
            __builtin_amdgcn_global_load_lds(GPTR(aA + (s + 1) * 32),
                                             LDSPTR(lds + nb * 4096 + wid * 512), 16, 0, 0);
            stage2(lds, 8192 + nb * 8192, wid, b0 + (s + 1) * 32, b1 + (s + 1) * 32);
        }
        if (pre) VMCNT3(); else VMCNT0();
        BARRIER();
        short8v av[4], bv[4];
        read_a4_128(lds, cur, wm, lane, av);
        read_b4_128(lds, cur, wn, lane, bv);
        __builtin_amdgcn_s_setprio(1);
        mfma16(av, bv, &acc[0]);
        __builtin_amdgcn_s_setprio(0);
        BARRIER();
    }
}

__device__ __forceinline__ float gelu_exact(float v) {
    return 0.5f * v * (1.0f + erff(v * 0.70710678118654752f));
}

// fast exact-GELU: A&S 7.1.26 erf (|err|<1.5e-7) + hw exp/rcp
__device__ __forceinline__ float gelu_fast(float x) {
    float z = 0.70710678118654752f * x;
    float az = fabsf(z);
    float t = __builtin_amdgcn_rcpf(1.0f + 0.3275911f * az);
    float poly = t * (0.254829592f + t * (-0.284496736f + t * (1.421413741f +
                 t * (-1.453152027f + t * 1.061405429f))));
    float erfv = 1.0f - poly * __expf(-az * az);
    erfv = (z < 0.0f) ? -erfv : erfv;
    return 0.5f * x * (1.0f + erfv);
}

// ---------------------------------------------------------------- GEMM1 2-phase 128x256 (row-major store epilogue)
__global__ __launch_bounds__(512, 4) void gemm1_2p(
    const bf16* __restrict__ xg, const bf16* __restrict__ xnb,
    const bf16* __restrict__ w1t,
    const float* __restrict__ spec_b1, const float* __restrict__ sh_b1,
    const int* __restrict__ e_of_tile,
    bf16* __restrict__ Hbuf, int y_base) {
    extern __shared__ bf16 lds[];
    int bx = blockIdx.x, by = blockIdx.y;
    int lt = by >> 1, half = by & 1;
    int y = y_base + lt;
    int tid = threadIdx.x, wid = tid >> 6, lane = tid & 63;
    int wm = wid >> 2, wn = wid & 3;
    int PA = tid;
    int LA = PA ^ ((PA >> 4) & 1) ^ (((PA >> 5) & 1) << 1);
    int ra = LA >> 2, ca = (LA & 3) * 8;
    int P0c = tid, P1c = 512 + tid;
    int L0 = P0c ^ ((P0c >> 4) & 1) ^ (((P0c >> 5) & 1) << 1);
    int L1 = P1c ^ ((P1c >> 4) & 1) ^ (((P1c >> 5) & 1) << 1);
    int rb0 = L0 >> 2, cb0 = (L0 & 3) * 8;
    int rb1 = L1 >> 2, cb1 = (L1 & 3) * 8;

    const bf16 *abase, *Bw;
    const float* bias;
    if (y < NTILE_MAX) {
        int e = e_of_tile[y];
        if (e < 0) return;
        abase = xg + (size_t)(y * 256 + half * 128) * DIM;
        Bw = w1t + (size_t)e * HID * DIM;
        bias = spec_b1 + (size_t)e * HID;
    } else {
        int ys = y - NTILE_MAX;
        int z = ys / NSDT, ry = ys % NSDT;
        abase = xnb + (size_t)(ry * 256 + half * 128) * DIM;
        Bw = w1t + (size_t)(4 + z) * HID * DIM;
        bias = sh_b1 + (size_t)z * HID;
    }
    const bf16* aA = abase + (size_t)ra * DIM + ca;
    const bf16* b0 = Bw + (size_t)(bx * 256 + rb0) * DIM + cb0;
    const bf16* b1 = Bw + (size_t)(bx * 256 + rb1) * DIM + cb1;

    f32x4 acc[4][4] = {};
    kloop2p<DIM / 32>(lds, aA, b0, b1, wm, wn, wid, lane, acc);

    bf16* hb = Hbuf + (size_t)(lt * 256 + half * 128) * HID;
    int fr = lane & 15, fq = lane >> 4;
    int cb = bx * 256 + wn * 64;
    float bvv[4];
    #pragma unroll
    for (int j = 0; j < 4; ++j) bvv[j] = bias[cb + j * 16 + fr];
    #pragma unroll
    for (int i = 0; i < 4; ++i) {
        #pragma unroll
        for (int rr = 0; rr < 4; ++rr) {
            int row = wm * 64 + i * 16 + fq * 4 + rr;
            bf16* hr = hb + (size_t)row * HID + cb + fr;
            #pragma unroll
            for (int j = 0; j < 4; ++j)
                hr[j * 16] = __float2bfloat16(gelu_fast(acc[i][j][rr] + bvv[j]));
        }
    }
}

// ---------------------------------------------------------------- GEMM2 8-phase 256x256 (row-major store epilogue)
__global__ __launch_bounds__(512, 2) void gemm2_8p(
    const bf16* __restrict__ Hbuf, const bf16* __restrict__ w2t,
    const float* __restrict__ spec_b2, const float* __restrict__ sh_b2,
    const int* __restrict__ e_of_tile, const float* __restrict__ slot_gate,
    const float* __restrict__ sh_probs,
    bf16* __restrict__ spec_g, bf16* __restrict__ shg, int y_base) {
    extern __shared__ bf16 lds[];
    int bx = blockIdx.x, by = blockIdx.y;
    int y = by + y_base;
    int tid = threadIdx.x, wid = tid >> 6, lane = tid & 63;
    int wm = wid >> 2, wn = wid & 3;
    int P0c = tid, P1c = 512 + tid;
    int L0 = P0c ^ ((P0c >> 4) & 1) ^ (((P0c >> 5) & 1) << 1);
    int L1 = P1c ^ ((P1c >> 4) & 1) ^ (((P1c >> 5) & 1) << 1);
    int r0 = L0 >> 2, c0 = (L0 & 3) * 8;
    int r1 = L1 >> 2, c1 = (L1 & 3) * 8;

    const bf16 *Bw;
    const float* bias;
    bf16* obase;
    bool grouped = (y < NTILE_MAX);
    int z = 0, ry = 0;
    if (grouped) {
        int e = e_of_tile[y];
        if (e < 0) return;
        Bw = w2t + (size_t)e * DIM * HID;
        bias = spec_b2 + (size_t)e * DIM;
        obase = spec_g + (size_t)y * 256 * DIM;
    } else {
        int ys = y - NTILE_MAX;
        z = ys / NSDT; ry = ys % NSDT;
        Bw = w2t + (size_t)(4 + z) * DIM * HID;
        bias = sh_b2 + (size_t)z * DIM;
        obase = shg + (size_t)(z * NTOK + ry * 256) * DIM;
    }
    const bf16* Ah = Hbuf + (size_t)by * 256 * HID;
    const bf16* a0 = Ah + (size_t)r0 * HID + c0;
    const bf16* a1 = Ah + (size_t)r1 * HID + c1;
    const bf16* b0 = Bw + (size_t)(bx * 256 + r0) * HID + c0;
    const bf16* b1 = Bw + (size_t)(bx * 256 + r1) * HID + c1;

    f32x4 acc[8][4] = {};
    kloop8p<HID / 64>(lds, a0, a1, b0, b1, wm, wn, wid, lane, acc);

    int fr = lane & 15, fq = lane >> 4;
    int cb = bx * 256 + wn * 64;
    float bvv[4];
    #pragma unroll
    for (int j = 0; j < 4; ++j) bvv[j] = bias[cb + j * 16 + fr];
    #pragma unroll
    for (int ii = 0; ii < 8; ++ii) {
        #pragma unroll
        for (int rr = 0; rr < 4; ++rr) {
            int row = wm * 128 + (ii >> 2) * 64 + (ii & 3) * 16 + fq * 4 + rr;
            float g = grouped ? slot_gate[y * 256 + row]
                              : sh_probs[(size_t)(ry * 256 + row) * 2 + z];
            bf16* orow = obase + (size_t)row * DIM + cb + fr;
            #pragma unroll
            for (int j = 0; j < 4; ++j)
                orow[j * 16] = __float2bfloat16(g * (acc[ii][j][rr] + bvv[j]));
        }
    }
}

// ---------------------------------------------------------------- plan-B dense fallback (128^2 m97, known-good)
__device__ __forceinline__ void stage_tile(const bf16* __restrict__ g, int ldg,
                                           bf16* lds, int tid) {
    int wave = tid >> 6, lane = tid & 63;
    #pragma unroll
    for (int q = 0; q < 2; ++q) {
        int chunk = wave * 2 + q;
        int row = chunk * 16 + (lane >> 2);
        int col = (lane & 3) * 8;
        __builtin_amdgcn_global_load_lds(GPTR(g + (size_t)row * ldg + col),
                                         LDSPTR(lds + chunk * 512), 16, 0, 0);
    }
}

__device__ __forceinline__ void mfma_step(const bf16* As, const bf16* Bs,
                                          int wr, int wc, int fr, int fq, f32x4 acc[4][4]) {
    short8v a[4], b[4];
    #pragma unroll
    for (int i = 0; i < 4; ++i) {
        a[i] = *(const short8v*)&As[(wr * 64 + i * 16 + fr) * 32 + fq * 8];
        b[i] = *(const short8v*)&Bs[(wc * 64 + i * 16 + fr) * 32 + fq * 8];
    }
    #pragma unroll
    for (int i = 0; i < 4; ++i)
        #pragma unroll
        for (int j = 0; j < 4; ++j)
            acc[i][j] = __builtin_amdgcn_mfma_f32_16x16x32_bf16(a[i], b[j], acc[i][j], 0, 0, 0);
}

__global__ __launch_bounds__(256) void gemm1_dense(
    const bf16* __restrict__ A, const bf16* __restrict__ BT,
    const float* __restrict__ bias, bf16* __restrict__ H) {
    __shared__ bf16 As[128 * 32];
    __shared__ bf16 Bs[128 * 32];
    int tid = threadIdx.x;
    int wid = tid >> 6, lane = tid & 63;
    int wr = wid >> 1, wc = wid & 1;
    int fr = lane & 15, fq = lane >> 4;
    const bf16* Ag = A + (size_t)(blockIdx.y * 128) * DIM;
    const bf16* Bg = BT + (size_t)(blockIdx.x * 128) * DIM;
    f32x4 acc[4][4] = {};
    for (int k0 = 0; k0 < DIM; k0 += 32) {
        stage_tile(Ag + k0, DIM, As, tid);
        stage_tile(Bg + k0, DIM, Bs, tid);
        __syncthreads();
        mfma_step(As, Bs, wr, wc, fr, fq, acc);
        __syncthreads();
    }
    int rbase = blockIdx.y * 128 + wr * 64;
    int cbase = blockIdx.x * 128 + wc * 64;
    #pragma unroll
    for (int j = 0; j < 4; ++j) {
        int col = cbase + j * 16 + fr;
        float bv = bias[col];
        #pragma unroll
        for (int i = 0; i < 4; ++i)
            #pragma unroll
            for (int r = 0; r < 4; ++r) {
                int row = rbase + i * 16 + fq * 4 + r;
                H[(size_t)row * HID + col] = __float2bfloat16(gelu_exact(acc[i][j][r] + bv));
            }
    }
}

__global__ __launch_bounds__(256) void gemm2_dense_out(
    const bf16* __restrict__ A, const bf16* __restrict__ BT,
    const float* __restrict__ bias, const float* __restrict__ gates,
    float* __restrict__ out, int gidx, int accum) {
    __shared__ bf16 As[128 * 32];
    __shared__ bf16 Bs[128 * 32];
    int tid = threadIdx.x;
    int wid = tid >> 6, lane = tid & 63;
    int wr = wid >> 1, wc = wid & 1;
    int fr = lane & 15, fq = lane >> 4;
    const bf16* Ag = A + (size_t)(blockIdx.y * 128) * HID;
    const bf16* Bg = BT + (size_t)(blockIdx.x * 128) * HID;
    f32x4 acc[4][4] = {};
    for (int k0 = 0; k0 < HID; k0 += 32) {
        stage_tile(Ag + k0, HID, As, tid);
        stage_tile(Bg + k0, HID, Bs, tid);
        __syncthreads();
        mfma_step(As, Bs, wr, wc, fr, fq, acc);
        __syncthreads();
    }
    int rbase = blockIdx.y * 128 + wr * 64;
    int cbase = blockIdx.x * 128 + wc * 64;
    #pragma unroll
    for (int j = 0; j < 4; ++j) {
        int col = cbase + j * 16 + fr;
        float bv = bias[col];
        #pragma unroll
        for (int i = 0; i < 4; ++i)
            #pragma unroll
            for (int r = 0; r < 4; ++r) {
                int row = rbase + i * 16 + fq * 4 + r;
                float g = gates[(size_t)row * 6 + gidx];
                float v = g * (acc[i][j][r] + bv);
                size_t idx = (size_t)row * DIM + col;
                out[idx] = accum ? out[idx] + v : v;
            }
    }
}

// ---------------------------------------------------------------- combine
__global__ void combine_kernel(const bf16* __restrict__ spec_g, const bf16* __restrict__ shg,
                               const int* __restrict__ back, float* __restrict__ out) {
    int idx = blockIdx.x * 256 + threadIdx.x;
    int tok = idx / 96;
    int c = (idx % 96) * 8;
    int b0 = back[2 * tok], b1 = back[2 * tok + 1];
    short8v q0 = *(const short8v*)&spec_g[(size_t)b0 * DIM + c];
    short8v q1 = *(const short8v*)&spec_g[(size_t)b1 * DIM + c];
    short8v s0 = *(const short8v*)&shg[(size_t)tok * DIM + c];
    short8v s1 = *(const short8v*)&shg[(size_t)(NTOK + tok) * DIM + c];
    float o[8];
    #pragma unroll
    for (int k = 0; k < 8; ++k) {
        float f0 = __uint_as_float((unsigned)(unsigned short)q0[k] << 16);
        float f1 = __uint_as_float((unsigned)(unsigned short)q1[k] << 16);
        float f2 = __uint_as_float((unsigned)(unsigned short)s0[k] << 16);
        float f3 = __uint_as_float((unsigned)(unsigned short)s1[k] << 16);
        o[k] = f0 + f1 + f2 + f3;
    }
    float* op = out + (size_t)tok * DIM + c;
    *(float4*)(op)     = *(const float4*)(o);
    *(float4*)(op + 4) = *(const float4*)(o + 4);
}

// ---------------------------------------------------------------- launch
static inline size_t align256(size_t x) { return (x + 255) & ~(size_t)255; }

extern "C" void kernel_launch(void* const* d_in, const int* in_sizes, int n_in,
                              void* d_out, int out_size, void* d_ws, size_t ws_size,
                              hipStream_t stream) {
    const float* x      = (const float*)d_in[0];
    const float* gamma  = (const float*)d_in[1];
    const float* beta   = (const float*)d_in[2];
    const float* srw    = (const float*)d_in[3];
    const float* srb    = (const float*)d_in[4];
    const float* spec_w1 = (const float*)d_in[5];
    const float* spec_b1 = (const float*)d_in[6];
    const float* spec_w2 = (const float*)d_in[7];
    const float* spec_b2 = (const float*)d_in[8];
    const float* shw    = (const float*)d_in[9];
    const float* shb    = (const float*)d_in[10];
    const float* sh_w1  = (const float*)d_in[11];
    const float* sh_b1  = (const float*)d_in[12];
    const float* sh_w2  = (const float*)d_in[13];
    const float* sh_b2  = (const float*)d_in[14];

    char* p = (char*)d_ws;
    size_t off = 0;
    bf16* xnb = (bf16*)(p + off);       off = align256(off + (size_t)NTOK * DIM * 2);
    bf16* w1t = (bf16*)(p + off);       off = align256(off + (size_t)6 * HID * DIM * 2);
    bf16* w2t = (bf16*)(p + off);       off = align256(off + (size_t)6 * DIM * HID * 2);
    int*  cnt2 = (int*)(p + off);       off = align256(off + (size_t)4 * NBKT * 4);
    float* gates = (float*)(p + off);   off = align256(off + (size_t)NTOK * 6 * 4);
    int*  tok2 = (int*)(p + off);       off = align256(off + (size_t)4 * NBKT * BKTCAP * 4);
    float* gate2 = (float*)(p + off);   off = align256(off + (size_t)4 * NBKT * BKTCAP * 4);
    int*  slot_tok = (int*)(p + off);   off = align256(off + (size_t)NSLOT_MAX * 4);
    float* slot_gate = (float*)(p + off); off = align256(off + (size_t)NSLOT_MAX * 4);
    int*  back = (int*)(p + off);       off = align256(off + (size_t)2 * NTOK * 4);
    int*  e_of_tile = (int*)(p + off);  off = align256(off + (size_t)NTILE_MAX * 4);
    bf16* spec_g = (bf16*)(p + off);    off = align256(off + (size_t)NSLOT_MAX * DIM * 2);
    bf16* shg   = (bf16*)(p + off);     off = align256(off + (size_t)2 * NTOK * DIM * 2);
    size_t fixed_end = off;
    bf16* Hbuf = (bf16*)(p + fixed_end);
    bf16* xg = spec_g;   // aliased: gather-write -> g1 read -> g2 write -> combine read

    const size_t tile_bytes = (size_t)256 * HID * 2;
    size_t avail = (ws_size > fixed_end) ? (ws_size - fixed_end) : 0;
    int tcap = (int)(avail / tile_bytes);
    if (tcap > NVT) tcap = NVT;

    float* out         = (float*)d_out;
    float* spec_logits = out + (size_t)NTOK * DIM;
    float* spec_probs  = spec_logits + (size_t)NTOK * 4;
    float* topk_idx    = spec_probs  + (size_t)NTOK * 4;
    float* topk_probs  = topk_idx    + (size_t)NTOK * 2;
    float* sh_logits   = topk_probs  + (size_t)NTOK * 2;
    float* sh_probs    = sh_logits   + (size_t)NTOK * 2;

    hipMemsetAsync(cnt2, 0, (size_t)4 * NBKT * 4, stream);
    prep_kernel<<<NCONVB + NTOK / 4, 256, 0, stream>>>(
        spec_w1, sh_w1, spec_w2, sh_w2, w1t, w2t, slot_tok, slot_gate,
        x, gamma, beta, srw, srb, shw, shb, xnb,
        spec_logits, spec_probs, topk_idx, topk_probs, sh_logits, sh_probs,
        gates, cnt2, tok2, gate2);

    if (tcap >= 8) {
        plan_kernel<<<1, 256, 0, stream>>>(cnt2, e_of_tile, tok2, gate2,
                                           slot_tok, slot_gate, back);
        gather_kernel<<<NSLOT_MAX * 96 / 256, 256, 0, stream>>>(xnb, slot_tok, xg);
        int csz = tcap >= 67 ? (NVT + 2) / 3 : (tcap < 64 ? tcap : 64);
        if (csz > tcap) csz = tcap;
        for (int c0 = 0; c0 < NVT; c0 += csz) {
            int n = NVT - c0 < csz ? NVT - c0 : csz;
            gemm1_2p<<<dim3(HID / 256, 2 * n), 512, LDSB1, stream>>>(
                xg, xnb, w1t, spec_b1, sh_b1, e_of_tile, Hbuf, c0);
            gemm2_8p<<<dim3(DIM / 256, n), 512, LDSB, stream>>>(
                Hbuf, w2t, spec_b2, sh_b2, e_of_tile, slot_gate, sh_probs,
                spec_g, shg, c0);
        }
        combine_kernel<<<NTOK * 96 / 256, 256, 0, stream>>>(spec_g, shg, back, out);
    } else {
        // plan B: dense 6-expert loop (reuses spec_g/shg region as H)
        bf16* HB = spec_g;
        for (int e = 0; e < 6; ++e) {
            const bf16* w1p = w1t + (size_t)e * HID * DIM;
            const bf16* w2p = w2t + (size_t)e * DIM * HID;
            const float* b1p = (e < 4) ? spec_b1 + (size_t)e * HID : sh_b1 + (size_t)(e - 4) * HID;
            const float* b2p = (e < 4) ? spec_b2 + (size_t)e * DIM : sh_b2 + (size_t)(e - 4) * DIM;
            gemm1_dense<<<dim3(HID / 128, NTOK / 128), 256, 0, stream>>>(xnb, w1p, b1p, HB);
            gemm2_dense_out<<<dim3(DIM / 128, NTOK / 128), 256, 0, stream>>>(
                HB, w2p, b2p, gates, out, e, e > 0);
        }
    }
}

// Round 17
// 764.376 us; speedup vs baseline: 1.1133x; 1.0260x over previous
//
#include <hip/hip_runtime.h>
#include <hip/hip_bf16.h>
#include <math.h>

#define NTOK 12544
#define DIM 768
#define HID 3072
#define NTILE_MAX 102               // spec 256-row tiles
#define NSLOT_MAX (NTILE_MAX * 256) // 26112 slots
#define NSDT 49                     // NTOK/256 dense row tiles per shared expert
#define NVT (NTILE_MAX + 2 * NSDT)  // 200 virtual 256-row tiles
#define NBKT 64
#define BKTCAP 256
#define LDSB 131072                 // gemm2 (256x256 8-phase)
#define LDSB1 49152                 // gemm1 (128x256 2-phase)
#define NCONVB 6912                 // conv blocks in prep_kernel (576*12)

typedef __hip_bfloat16 bf16;
typedef __attribute__((ext_vector_type(8))) short short8v;
typedef __attribute__((ext_vector_type(4))) float f32x4;

#define GPTR(p)  ((const __attribute__((address_space(1))) void*)(p))
#define LDSPTR(p) ((__attribute__((address_space(3))) void*)(p))

// ---------------------------------------------------------------- prep: conv (bid<NCONVB) + router_ln (else)
__global__ __launch_bounds__(256) void prep_kernel(
    const float* __restrict__ spec_w1, const float* __restrict__ sh_w1,
    const float* __restrict__ spec_w2, const float* __restrict__ sh_w2,
    bf16* __restrict__ w1t, bf16* __restrict__ w2t,
    int* __restrict__ slot_tok, float* __restrict__ slot_gate,
    const float* __restrict__ x,
    const float* __restrict__ lng, const float* __restrict__ lnb,
    const float* __restrict__ srw, const float* __restrict__ srb,
    const float* __restrict__ shw, const float* __restrict__ shb,
    bf16* __restrict__ xnb,
    float* __restrict__ spec_logits, float* __restrict__ spec_probs,
    float* __restrict__ topk_idx, float* __restrict__ topk_probs,
    float* __restrict__ sh_logits, float* __restrict__ sh_probs,
    float* __restrict__ gates,
    int* __restrict__ cnt2, int* __restrict__ tok2, float* __restrict__ gate2) {
    __shared__ float tile[64][65];
    int bid = blockIdx.x;
    int t = threadIdx.x;
    if (bid < NCONVB) {
        int z = bid / 576, ti = bid % 576;
        if (z == 0 && ti < NTILE_MAX) {
            int s = ti * 256 + t;
            slot_tok[s] = 0; slot_gate[s] = 0.0f;
        }
        const float* src; bf16* dst; int R, C, tr, tc;
        if (z < 6) {
            R = DIM; C = HID;
            src = (z < 4) ? spec_w1 + (size_t)z * R * C : sh_w1 + (size_t)(z - 4) * R * C;
            dst = w1t + (size_t)z * R * C;
            tr = ti % 12; tc = ti / 12;
        } else {
            int e = z - 6;
            R = HID; C = DIM;
            src = (e < 4) ? spec_w2 + (size_t)e * R * C : sh_w2 + (size_t)(e - 4) * R * C;
            dst = w2t + (size_t)e * R * C;
            tr = ti % 48; tc = ti / 48;
        }
        int r0 = tr * 64, c0 = tc * 64;
        int lr = t >> 4, lc = (t & 15) * 4;
        #pragma unroll
        for (int ii = 0; ii < 4; ++ii) {
            float4 v = *(const float4*)&src[(size_t)(r0 + lr + 16 * ii) * C + c0 + lc];
            tile[lc + 0][lr + 16 * ii] = v.x;
            tile[lc + 1][lr + 16 * ii] = v.y;
            tile[lc + 2][lr + 16 * ii] = v.z;
            tile[lc + 3][lr + 16 * ii] = v.w;
        }
        __syncthreads();
        int oc = t >> 4, orr = (t & 15) * 4;
        #pragma unroll
        for (int ii = 0; ii < 4; ++ii) {
            union { ushort4 u4; bf16 h[4]; } pk;
            #pragma unroll
            for (int k = 0; k < 4; ++k)
                pk.h[k] = __float2bfloat16(tile[oc + 16 * ii][orr + k]);
            *(ushort4*)&dst[(size_t)(c0 + oc + 16 * ii) * R + r0 + orr] = pk.u4;
        }
        return;
    }
    int rid = bid - NCONVB;
    int tok = rid * 4 + (t >> 6);
    int bucket = rid & (NBKT - 1);
    int lane = t & 63;
    const float* xr = x + (size_t)tok * DIM;
    bf16* xb = xnb + (size_t)tok * DIM;
    float v[12];
    float s = 0.0f;
    #pragma unroll
    for (int i = 0; i < 6; ++i) {
        float2 xv = *(const float2*)&xr[lane * 2 + 128 * i];
        v[2 * i] = xv.x; v[2 * i + 1] = xv.y;
        s += xv.x + xv.y;
    }
    #pragma unroll
    for (int o = 32; o > 0; o >>= 1) s += __shfl_xor(s, o, 64);
    float mean = s * (1.0f / 768.0f);
    float sq = 0.0f;
    #pragma unroll
    for (int i = 0; i < 12; ++i) { float d = v[i] - mean; sq += d * d; }
    #pragma unroll
    for (int o = 32; o > 0; o >>= 1) sq += __shfl_xor(sq, o, 64);
    float rstd = rsqrtf(sq * (1.0f / 768.0f) + 1e-5f);

    float acc[6] = {0, 0, 0, 0, 0, 0};
    #pragma unroll
    for (int i = 0; i < 6; ++i) {
        int d0 = lane * 2 + 128 * i;
        float xn0 = (v[2 * i]     - mean) * rstd * lng[d0]     + lnb[d0];
        float xn1 = (v[2 * i + 1] - mean) * rstd * lng[d0 + 1] + lnb[d0 + 1];
        union { unsigned u; bf16 h[2]; } pk;
        pk.h[0] = __float2bfloat16(xn0);
        pk.h[1] = __float2bfloat16(xn1);
        *(unsigned*)&xb[d0] = pk.u;
        float4 a = *(const float4*)&srw[d0 * 4];
        float4 b = *(const float4*)&srw[d0 * 4 + 4];
        acc[0] += xn0 * a.x + xn1 * b.x;
        acc[1] += xn0 * a.y + xn1 * b.y;
        acc[2] += xn0 * a.z + xn1 * b.z;
        acc[3] += xn0 * a.w + xn1 * b.w;
        float4 sw = *(const float4*)&shw[d0 * 2];
        acc[4] += xn0 * sw.x + xn1 * sw.z;
        acc[5] += xn0 * sw.y + xn1 * sw.w;
    }
    #pragma unroll
    for (int j = 0; j < 6; ++j) {
        #pragma unroll
        for (int o = 32; o > 0; o >>= 1) acc[j] += __shfl_xor(acc[j], o, 64);
    }
    if (lane == 0) {
        float l[4];
        #pragma unroll
        for (int j = 0; j < 4; ++j) l[j] = acc[j] + srb[j];
        float m = fmaxf(fmaxf(l[0], l[1]), fmaxf(l[2], l[3]));
        float e[4], ssum = 0.0f;
        #pragma unroll
        for (int j = 0; j < 4; ++j) { e[j] = expf(l[j] - m); ssum += e[j]; }
        float inv = 1.0f / ssum;
        float p[4];
        #pragma unroll
        for (int j = 0; j < 4; ++j) p[j] = e[j] * inv;
        int i0 = 0;
        for (int j = 1; j < 4; ++j) if (p[j] > p[i0]) i0 = j;
        int i1 = -1;
        for (int j = 0; j < 4; ++j) {
            if (j == i0) continue;
            if (i1 < 0 || p[j] > p[i1]) i1 = j;
        }
        float sl0 = acc[4] + shb[0], sl1 = acc[5] + shb[1];
        float sm = fmaxf(sl0, sl1);
        float se0 = expf(sl0 - sm), se1 = expf(sl1 - sm);
        float sinv = 1.0f / (se0 + se1);
        float sp0 = se0 * sinv, sp1 = se1 * sinv;

        #pragma unroll
        for (int j = 0; j < 4; ++j) {
            spec_logits[tok * 4 + j] = l[j];
            spec_probs[tok * 4 + j]  = p[j];
        }
        topk_idx[tok * 2 + 0]   = (float)i0;
        topk_idx[tok * 2 + 1]   = (float)i1;
        topk_probs[tok * 2 + 0] = p[i0];
        topk_probs[tok * 2 + 1] = p[i1];
        sh_logits[tok * 2 + 0]  = sl0;
        sh_logits[tok * 2 + 1]  = sl1;
        sh_probs[tok * 2 + 0]   = sp0;
        sh_probs[tok * 2 + 1]   = sp1;
        float gg[6] = {0, 0, 0, 0, sp0, sp1};
        gg[i0] = p[i0];
        gg[i1] = p[i1];
        #pragma unroll
        for (int j = 0; j < 6; ++j) gates[tok * 6 + j] = gg[j];
        int c0 = i0 * NBKT + bucket;
        int pos0 = atomicAdd(&cnt2[c0], 1);
        tok2[c0 * BKTCAP + pos0]  = tok * 2 + 0;
        gate2[c0 * BKTCAP + pos0] = p[i0];
        int c1 = i1 * NBKT + bucket;
        int pos1 = atomicAdd(&cnt2[c1], 1);
        tok2[c1 * BKTCAP + pos1]  = tok * 2 + 1;
        gate2[c1 * BKTCAP + pos1] = p[i1];
    }
}

// ---------------------------------------------------------------- plan: bucket scan, 256-row padded compact
__global__ void plan_kernel(const int* __restrict__ cnt2, int* __restrict__ e_of_tile,
                            const int* __restrict__ tok2, const float* __restrict__ gate2,
                            int* __restrict__ slot_tok, float* __restrict__ slot_gate,
                            int* __restrict__ back) {
    __shared__ int sbase[4 * NBKT];
    __shared__ int offsE[5];
    __shared__ int etot[4];
    int tid = threadIdx.x, lane = tid & 63, wid = tid >> 6;
    int c = cnt2[wid * NBKT + lane];
    int inc = c;
    #pragma unroll
    for (int o = 1; o < 64; o <<= 1) {
        int tv = __shfl_up(inc, o, 64);
        if (lane >= o) inc += tv;
    }
    int exc = inc - c;
    if (lane == 63) etot[wid] = inc;
    __syncthreads();
    if (tid == 0) {
        int o = 0;
        for (int e = 0; e < 4; ++e) { offsE[e] = o; o += (etot[e] + 255) & ~255; }
        offsE[4] = o;
    }
    __syncthreads();
    sbase[tid] = offsE[wid] + exc;
    for (int idx = tid; idx < NTILE_MAX; idx += 256) {
        int s0 = idx * 256, e = -1;
        for (int j = 0; j < 4; ++j)
            if (s0 >= offsE[j] && s0 < offsE[j + 1]) e = j;
        e_of_tile[idx] = e;
    }
    __syncthreads();
    int bs = sbase[tid];
    int cc = cnt2[tid];
    for (int i = 0; i < cc; ++i) {
        int gs = bs + i;
        int tk = tok2[tid * BKTCAP + i];
        slot_tok[gs] = tk >> 1;
        slot_gate[gs] = gate2[tid * BKTCAP + i];
        back[tk] = gs;
    }
}

// ---------------------------------------------------------------- gather: pack spec-slot A rows into xg (aliased w/ spec_g)
__global__ void gather_kernel(const bf16* __restrict__ xnb, const int* __restrict__ slot_tok,
                              bf16* __restrict__ xg) {
    int idx = blockIdx.x * 256 + threadIdx.x;
    int slot = idx / 96;
    int c = (idx % 96) * 8;
    int tok = slot_tok[slot];
    *(short8v*)&xg[(size_t)slot * DIM + c] = *(const short8v*)&xnb[(size_t)tok * DIM + c];
}

// ================================================================ shared MFMA helpers
__device__ __forceinline__ int swz(int off) {
    return off ^ (((off >> 8) & 1) << 4) ^ (((off >> 9) & 1) << 5);
}

__device__ __forceinline__ void stage2(bf16* lds, int base_elems, int wid,
                                       const bf16* s0, const bf16* s1) {
    __builtin_amdgcn_global_load_lds(GPTR(s0), LDSPTR(lds + base_elems + wid * 512), 16, 0, 0);
    __builtin_amdgcn_global_load_lds(GPTR(s1), LDSPTR(lds + base_elems + 4096 + wid * 512), 16, 0, 0);
}

__device__ __forceinline__ void mfma16(const short8v a[4], const short8v b[4], f32x4 (*am)[4]) {
    #pragma unroll
    for (int i = 0; i < 4; ++i)
        #pragma unroll
        for (int j = 0; j < 4; ++j)
            am[i][j] = __builtin_amdgcn_mfma_f32_16x16x32_bf16(a[i], b[j], am[i][j], 0, 0, 0);
}

#define BARRIER() __builtin_amdgcn_s_barrier()
#define VMCNT4() asm volatile("s_waitcnt vmcnt(4)" ::: "memory")
#define VMCNT3() asm volatile("s_waitcnt vmcnt(3)" ::: "memory")
#define VMCNT0() asm volatile("s_waitcnt vmcnt(0)" ::: "memory")

// ================================================================ 256x256 8-phase core (gemm2, refcheck'd R8-R16)
__device__ __forceinline__ void read_a4(const bf16* lds, int buf, int ks, int wm, int mh,
                                        int lane, short8v a[4]) {
    const char* base = (const char*)lds + buf * 32768 + ks * 16384;
    #pragma unroll
    for (int i = 0; i < 4; ++i) {
        int off = (wm * 128 + mh * 64 + i * 16 + (lane & 15)) * 64 + ((lane >> 4) * 16);
        a[i] = *(const short8v*)(base + swz(off));
    }
}

__device__ __forceinline__ void read_b4(const bf16* lds, int buf, int ks, int wn,
                                        int lane, short8v b[4]) {
    const char* base = (const char*)lds + 65536 + buf * 32768 + ks * 16384;
    #pragma unroll
    for (int j = 0; j < 4; ++j) {
        int off = (wn * 64 + j * 16 + (lane & 15)) * 64 + ((lane >> 4) * 16);
        b[j] = *(const short8v*)(base + swz(off));
    }
}

template<int NT>
__device__ __forceinline__ void kloop8p(bf16* lds, const bf16* a0, const bf16* a1,
                                        const bf16* b0, const bf16* b1,
                                        int wm, int wn, int wid, int lane,
                                        f32x4 acc[8][4]) {
    stage2(lds, 0, wid, a0, a1);
    stage2(lds, 32768, wid, b0, b1);
    stage2(lds, 8192, wid, a0 + 32, a1 + 32);
    stage2(lds, 32768 + 8192, wid, b0 + 32, b1 + 32);
    VMCNT4();
    BARRIER();
    for (int t = 0; t < NT; ++t) {
        int buf = t & 1, nb = buf ^ 1;
        bool pre = (t + 1 < NT);
        short8v af[4], bfv[4];
        if (pre) stage2(lds, nb * 16384, wid, a0 + (t + 1) * 64, a1 + (t + 1) * 64);
        read_a4(lds, buf, 0, wm, 0, lane, af);
        read_b4(lds, buf, 0, wn, lane, bfv);
        BARRIER();
        __builtin_amdgcn_s_setprio(1);
        mfma16(af, bfv, &acc[0]);
        __builtin_amdgcn_s_setprio(0);
        BARRIER();
        if (pre) stage2(lds, 32768 + nb * 16384, wid, b0 + (t + 1) * 64, b1 + (t + 1) * 64);
        read_a4(lds, buf, 0, wm, 1, lane, af);
        BARRIER();
        __builtin_amdgcn_s_setprio(1);
        mfma16(af, bfv, &acc[4]);
        __builtin_amdgcn_s_setprio(0);
        if (pre) VMCNT4(); else VMCNT0();
        BARRIER();
        if (pre) stage2(lds, nb * 16384 + 8192, wid, a0 + (t + 1) * 64 + 32, a1 + (t + 1) * 64 + 32);
        read_a4(lds, buf, 1, wm, 0, lane, af);
        read_b4(lds, buf, 1, wn, lane, bfv);
        BARRIER();
        __builtin_amdgcn_s_setprio(1);
        mfma16(af, bfv, &acc[0]);
        __builtin_amdgcn_s_setprio(0);
        BARRIER();
        if (pre) stage2(lds, 32768 + nb * 16384 + 8192, wid, b0 + (t + 1) * 64 + 32, b1 + (t + 1) * 64 + 32);
        read_a4(lds, buf, 1, wm, 1, lane, af);
        BARRIER();
        __builtin_amdgcn_s_setprio(1);
        mfma16(af, bfv, &acc[4]);
        __builtin_amdgcn_s_setprio(0);
        if (pre) VMCNT4();
        BARRIER();
    }
}

// ================================================================ 128x256 2-phase core (gemm1, refcheck'd R13)
__device__ __forceinline__ void read_a4_128(const bf16* lds, int cur, int wm,
                                            int lane, short8v a[4]) {
    const char* base = (const char*)lds + cur * 8192;
    #pragma unroll
    for (int i = 0; i < 4; ++i) {
        int off = (wm * 64 + i * 16 + (lane & 15)) * 64 + ((lane >> 4) * 16);
        a[i] = *(const short8v*)(base + swz(off));
    }
}

__device__ __forceinline__ void read_b4_128(const bf16* lds, int cur, int wn,
                                            int lane, short8v b[4]) {
    const char* base = (const char*)lds + 16384 + cur * 16384;
    #pragma unroll
    for (int j = 0; j < 4; ++j) {
        int off = (wn * 64 + j * 16 + (lane & 15)) * 64 + ((lane >> 4) * 16);
        b[j] = *(const short8v*)(base + swz(off));
    }
}

template<int NS>
__device__ __forceinline__ void kloop2p(bf16* lds, const bf16* aA,
                                        const bf16* b0, const bf16* b1,
                                        int wm, int wn, int wid, int lane,
                                        f32x4 acc[4][4]) {
    __builtin_amdgcn_global_load_lds(GPTR(aA), LDSPTR(lds + wid * 512), 16, 0, 0);
    stage2(lds, 8192, wid, b0, b1);
    for (int s = 0; s < NS; ++s) {
        int cur = s & 1, nb = cur ^ 1;
        bool pre = (s + 1 < NS);
        if (pre) {
            __builtin_amdgcn_global_load_lds(GPTR(aA + (s + 1) * 32),
                                             LDSPTR(lds + nb * 4096 + wid * 512), 16, 0, 0);
            stage2(lds, 8192 + nb * 8192, wid, b0 + (s + 1) * 32, b1 + (s + 1) * 32);
        }
        if (pre) VMCNT3(); else VMCNT0();
        BARRIER();
        short8v av[4], bv[4];
        read_a4_128(lds, cur, wm, lane, av);
        read_b4_128(lds, cur, wn, lane, bv);
        __builtin_amdgcn_s_setprio(1);
        mfma16(av, bv, &acc[0]);
        __builtin_amdgcn_s_setprio(0);
        BARRIER();
    }
}

__device__ __forceinline__ float gelu_exact(float v) {
    return 0.5f * v * (1.0f + erff(v * 0.70710678118654752f));
}

// fast exact-GELU (fallback path): A&S 7.1.26 erf + hw exp/rcp
__device__ __forceinline__ float gelu_fast(float x) {
    float z = 0.70710678118654752f * x;
    float az = fabsf(z);
    float t = __builtin_amdgcn_rcpf(1.0f + 0.3275911f * az);
    float poly = t * (0.254829592f + t * (-0.284496736f + t * (1.421413741f +
                 t * (-1.453152027f + t * 1.061405429f))));
    float erfv = 1.0f - poly * __expf(-az * az);
    erfv = (z < 0.0f) ? -erfv : erfv;
    return 0.5f * x * (1.0f + erfv);
}

// tanh-form GELU via hw exp2 (7 VALU ops, max |err| ~3e-4 vs exact):
// gelu(x) = x * sigmoid(1.5957691(x + 0.044715 x^3))
//         = x * rcp(1 + exp2(-x*(2.3021858 + 0.1029131 x^2)))
__device__ __forceinline__ float gelu_tanh(float x) {
    float x2 = x * x;
    float un = x * fmaf(x2, -0.10291313f, -2.30218576f);
    float e = exp2f(un);
    return x * __builtin_amdgcn_rcpf(1.0f + e);
}

// ---------------------------------------------------------------- GEMM1 2-phase 128x256 (tanh-GELU epilogue)
__global__ __launch_bounds__(512, 4) void gemm1_2p(
    const bf16* __restrict__ xg, const bf16* __restrict__ xnb,
    const bf16* __restrict__ w1t,
    const float* __restrict__ spec_b1, const float* __restrict__ sh_b1,
    const int* __restrict__ e_of_tile,
    bf16* __restrict__ Hbuf, int y_base) {
    extern __shared__ bf16 lds[];
    int bx = blockIdx.x, by = blockIdx.y;
    int lt = by >> 1, half = by & 1;
    int y = y_base + lt;
    int tid = threadIdx.x, wid = tid >> 6, lane = tid & 63;
    int wm = wid >> 2, wn = wid & 3;
    int PA = tid;
    int LA = PA ^ ((PA >> 4) & 1) ^ (((PA >> 5) & 1) << 1);
    int ra = LA >> 2, ca = (LA & 3) * 8;
    int P0c = tid, P1c = 512 + tid;
    int L0 = P0c ^ ((P0c >> 4) & 1) ^ (((P0c >> 5) & 1) << 1);
    int L1 = P1c ^ ((P1c >> 4) & 1) ^ (((P1c >> 5) & 1) << 1);
    int rb0 = L0 >> 2, cb0 = (L0 & 3) * 8;
    int rb1 = L1 >> 2, cb1 = (L1 & 3) * 8;

    const bf16 *abase, *Bw;
    const float* bias;
    if (y < NTILE_MAX) {
        int e = e_of_tile[y];
        if (e < 0) return;
        abase = xg + (size_t)(y * 256 + half * 128) * DIM;
        Bw = w1t + (size_t)e * HID * DIM;
        bias = spec_b1 + (size_t)e * HID;
    } else {
        int ys = y - NTILE_MAX;
        int z = ys / NSDT, ry = ys % NSDT;
        abase = xnb + (size_t)(ry * 256 + half * 128) * DIM;
        Bw = w1t + (size_t)(4 + z) * HID * DIM;
        bias = sh_b1 + (size_t)z * HID;
    }
    const bf16* aA = abase + (size_t)ra * DIM + ca;
    const bf16* b0 = Bw + (size_t)(bx * 256 + rb0) * DIM + cb0;
    const bf16* b1 = Bw + (size_t)(bx * 256 + rb1) * DIM + cb1;

    f32x4 acc[4][4] = {};
    kloop2p<DIM / 32>(lds, aA, b0, b1, wm, wn, wid, lane, acc);

    bf16* hb = Hbuf + (size_t)(lt * 256 + half * 128) * HID;
    int fr = lane & 15, fq = lane >> 4;
    int cb = bx * 256 + wn * 64;
    float bvv[4];
    #pragma unroll
    for (int j = 0; j < 4; ++j) bvv[j] = bias[cb + j * 16 + fr];
    #pragma unroll
    for (int i = 0; i < 4; ++i) {
        #pragma unroll
        for (int rr = 0; rr < 4; ++rr) {
            int row = wm * 64 + i * 16 + fq * 4 + rr;
            bf16* hr = hb + (size_t)row * HID + cb + fr;
            #pragma unroll
            for (int j = 0; j < 4; ++j)
                hr[j * 16] = __float2bfloat16(gelu_tanh(acc[i][j][rr] + bvv[j]));
        }
    }
}

// ---------------------------------------------------------------- GEMM2 8-phase 256x256 (row-major store epilogue)
__global__ __launch_bounds__(512, 2) void gemm2_8p(
    const bf16* __restrict__ Hbuf, const bf16* __restrict__ w2t,
    const float* __restrict__ spec_b2, const float* __restrict__ sh_b2,
    const int* __restrict__ e_of_tile, const float* __restrict__ slot_gate,
    const float* __restrict__ sh_probs,
    bf16* __restrict__ spec_g, bf16* __restrict__ shg, int y_base) {
    extern __shared__ bf16 lds[];
    int bx = blockIdx.x, by = blockIdx.y;
    int y = by + y_base;
    int tid = threadIdx.x, wid = tid >> 6, lane = tid & 63;
    int wm = wid >> 2, wn = wid & 3;
    int P0c = tid, P1c = 512 + tid;
    int L0 = P0c ^ ((P0c >> 4) & 1) ^ (((P0c >> 5) & 1) << 1);
    int L1 = P1c ^ ((P1c >> 4) & 1) ^ (((P1c >> 5) & 1) << 1);
    int r0 = L0 >> 2, c0 = (L0 & 3) * 8;
    int r1 = L1 >> 2, c1 = (L1 & 3) * 8;

    const bf16 *Bw;
    const float* bias;
    bf16* obase;
    bool grouped = (y < NTILE_MAX);
    int z = 0, ry = 0;
    if (grouped) {
        int e = e_of_tile[y];
        if (e < 0) return;
        Bw = w2t + (size_t)e * DIM * HID;
        bias = spec_b2 + (size_t)e * DIM;
        obase = spec_g + (size_t)y * 256 * DIM;
    } else {
        int ys = y - NTILE_MAX;
        z = ys / NSDT; ry = ys % NSDT;
        Bw = w2t + (size_t)(4 + z) * DIM * HID;
        bias = sh_b2 + (size_t)z * DIM;
        obase = shg + (size_t)(z * NTOK + ry * 256) * DIM;
    }
    const bf16* Ah = Hbuf + (size_t)by * 256 * HID;
    const bf16* a0 = Ah + (size_t)r0 * HID + c0;
    const bf16* a1 = Ah + (size_t)r1 * HID + c1;
    const bf16* b0 = Bw + (size_t)(bx * 256 + r0) * HID + c0;
    const bf16* b1 = Bw + (size_t)(bx * 256 + r1) * HID + c1;

    f32x4 acc[8][4] = {};
    kloop8p<HID / 64>(lds, a0, a1, b0, b1, wm, wn, wid, lane, acc);

    int fr = lane & 15, fq = lane >> 4;
    int cb = bx * 256 + wn * 64;
    float bvv[4];
    #pragma unroll
    for (int j = 0; j < 4; ++j) bvv[j] = bias[cb + j * 16 + fr];
    #pragma unroll
    for (int ii = 0; ii < 8; ++ii) {
        #pragma unroll
        for (int rr = 0; rr < 4; ++rr) {
            int row = wm * 128 + (ii >> 2) * 64 + (ii & 3) * 16 + fq * 4 + rr;
            float g = grouped ? slot_gate[y * 256 + row]
                              : sh_probs[(size_t)(ry * 256 + row) * 2 + z];
            bf16* orow = obase + (size_t)row * DIM + cb + fr;
            #pragma unroll
            for (int j = 0; j < 4; ++j)
                orow[j * 16] = __float2bfloat16(g * (acc[ii][j][rr] + bvv[j]));
        }
    }
}

// ---------------------------------------------------------------- plan-B dense fallback (128^2 m97, known-good)
__device__ __forceinline__ void stage_tile(const bf16* __restrict__ g, int ldg,
                                           bf16* lds, int tid) {
    int wave = tid >> 6, lane = tid & 63;
    #pragma unroll
    for (int q = 0; q < 2; ++q) {
        int chunk = wave * 2 + q;
        int row = chunk * 16 + (lane >> 2);
        int col = (lane & 3) * 8;
        __builtin_amdgcn_global_load_lds(GPTR(g + (size_t)row * ldg + col),
                                         LDSPTR(lds + chunk * 512), 16, 0, 0);
    }
}

__device__ __forceinline__ void mfma_step(const bf16* As, const bf16* Bs,
                                          int wr, int wc, int fr, int fq, f32x4 acc[4][4]) {
    short8v a[4], b[4];
    #pragma unroll
    for (int i = 0; i < 4; ++i) {
        a[i] = *(const short8v*)&As[(wr * 64 + i * 16 + fr) * 32 + fq * 8];
        b[i] = *(const short8v*)&Bs[(wc * 64 + i * 16 + fr) * 32 + fq * 8];
    }
    #pragma unroll
    for (int i = 0; i < 4; ++i)
        #pragma unroll
        for (int j = 0; j < 4; ++j)
            acc[i][j] = __builtin_amdgcn_mfma_f32_16x16x32_bf16(a[i], b[j], acc[i][j], 0, 0, 0);
}

__global__ __launch_bounds__(256) void gemm1_dense(
    const bf16* __restrict__ A, const bf16* __restrict__ BT,
    const float* __restrict__ bias, bf16* __restrict__ H) {
    __shared__ bf16 As[128 * 32];
    __shared__ bf16 Bs[128 * 32];
    int tid = threadIdx.x;
    int wid = tid >> 6, lane = tid & 63;
    int wr = wid >> 1, wc = wid & 1;
    int fr = lane & 15, fq = lane >> 4;
    const bf16* Ag = A + (size_t)(blockIdx.y * 128) * DIM;
    const bf16* Bg = BT + (size_t)(blockIdx.x * 128) * DIM;
    f32x4 acc[4][4] = {};
    for (int k0 = 0; k0 < DIM; k0 += 32) {
        stage_tile(Ag + k0, DIM, As, tid);
        stage_tile(Bg + k0, DIM, Bs, tid);
        __syncthreads();
        mfma_step(As, Bs, wr, wc, fr, fq, acc);
        __syncthreads();
    }
    int rbase = blockIdx.y * 128 + wr * 64;
    int cbase = blockIdx.x * 128 + wc * 64;
    #pragma unroll
    for (int j = 0; j < 4; ++j) {
        int col = cbase + j * 16 + fr;
        float bv = bias[col];
        #pragma unroll
        for (int i = 0; i < 4; ++i)
            #pragma unroll
            for (int r = 0; r < 4; ++r) {
                int row = rbase + i * 16 + fq * 4 + r;
                H[(size_t)row * HID + col] = __float2bfloat16(gelu_exact(acc[i][j][r] + bv));
            }
    }
}

__global__ __launch_bounds__(256) void gemm2_dense_out(
    const bf16* __restrict__ A, const bf16* __restrict__ BT,
    const float* __restrict__ bias, const float* __restrict__ gates,
    float* __restrict__ out, int gidx, int accum) {
    __shared__ bf16 As[128 * 32];
    __shared__ bf16 Bs[128 * 32];
    int tid = threadIdx.x;
    int wid = tid >> 6, lane = tid & 63;
    int wr = wid >> 1, wc = wid & 1;
    int fr = lane & 15, fq = lane >> 4;
    const bf16* Ag = A + (size_t)(blockIdx.y * 128) * HID;
    const bf16* Bg = BT + (size_t)(blockIdx.x * 128) * HID;
    f32x4 acc[4][4] = {};
    for (int k0 = 0; k0 < HID; k0 += 32) {
        stage_tile(Ag + k0, HID, As, tid);
        stage_tile(Bg + k0, HID, Bs, tid);
        __syncthreads();
        mfma_step(As, Bs, wr, wc, fr, fq, acc);
        __syncthreads();
    }
    int rbase = blockIdx.y * 128 + wr * 64;
    int cbase = blockIdx.x * 128 + wc * 64;
    #pragma unroll
    for (int j = 0; j < 4; ++j) {
        int col = cbase + j * 16 + fr;
        float bv = bias[col];
        #pragma unroll
        for (int i = 0; i < 4; ++i)
            #pragma unroll
            for (int r = 0; r < 4; ++r) {
                int row = rbase + i * 16 + fq * 4 + r;
                float g = gates[(size_t)row * 6 + gidx];
                float v = g * (acc[i][j][r] + bv);
                size_t idx = (size_t)row * DIM + col;
                out[idx] = accum ? out[idx] + v : v;
            }
    }
}

// ---------------------------------------------------------------- combine
__global__ void combine_kernel(const bf16* __restrict__ spec_g, const bf16* __restrict__ shg,
                               const int* __restrict__ back, float* __restrict__ out) {
    int idx = blockIdx.x * 256 + threadIdx.x;
    int tok = idx / 96;
    int c = (idx % 96) * 8;
    int b0 = back[2 * tok], b1 = back[2 * tok + 1];
    short8v q0 = *(const short8v*)&spec_g[(size_t)b0 * DIM + c];
    short8v q1 = *(const short8v*)&spec_g[(size_t)b1 * DIM + c];
    short8v s0 = *(const short8v*)&shg[(size_t)tok * DIM + c];
    short8v s1 = *(const short8v*)&shg[(size_t)(NTOK + tok) * DIM + c];
    float o[8];
    #pragma unroll
    for (int k = 0; k < 8; ++k) {
        float f0 = __uint_as_float((unsigned)(unsigned short)q0[k] << 16);
        float f1 = __uint_as_float((unsigned)(unsigned short)q1[k] << 16);
        float f2 = __uint_as_float((unsigned)(unsigned short)s0[k] << 16);
        float f3 = __uint_as_float((unsigned)(unsigned short)s1[k] << 16);
        o[k] = f0 + f1 + f2 + f3;
    }
    float* op = out + (size_t)tok * DIM + c;
    *(float4*)(op)     = *(const float4*)(o);
    *(float4*)(op + 4) = *(const float4*)(o + 4);
}

// ---------------------------------------------------------------- launch
static inline size_t align256(size_t x) { return (x + 255) & ~(size_t)255; }

extern "C" void kernel_launch(void* const* d_in, const int* in_sizes, int n_in,
                              void* d_out, int out_size, void* d_ws, size_t ws_size,
                              hipStream_t stream) {
    const float* x      = (const float*)d_in[0];
    const float* gamma  = (const float*)d_in[1];
    const float* beta   = (const float*)d_in[2];
    const float* srw    = (const float*)d_in[3];
    const float* srb    = (const float*)d_in[4];
    const float* spec_w1 = (const float*)d_in[5];
    const float* spec_b1 = (const float*)d_in[6];
    const float* spec_w2 = (const float*)d_in[7];
    const float* spec_b2 = (const float*)d_in[8];
    const float* shw    = (const float*)d_in[9];
    const float* shb    = (const float*)d_in[10];
    const float* sh_w1  = (const float*)d_in[11];
    const float* sh_b1  = (const float*)d_in[12];
    const float* sh_w2  = (const float*)d_in[13];
    const float* sh_b2  = (const float*)d_in[14];

    char* p = (char*)d_ws;
    size_t off = 0;
    bf16* xnb = (bf16*)(p + off);       off = align256(off + (size_t)NTOK * DIM * 2);
    bf16* w1t = (bf16*)(p + off);       off = align256(off + (size_t)6 * HID * DIM * 2);
    bf16* w2t = (bf16*)(p + off);       off = align256(off + (size_t)6 * DIM * HID * 2);
    int*  cnt2 = (int*)(p + off);       off = align256(off + (size_t)4 * NBKT * 4);
    float* gates = (float*)(p + off);   off = align256(off + (size_t)NTOK * 6 * 4);
    int*  tok2 = (int*)(p + off);       off = align256(off + (size_t)4 * NBKT * BKTCAP * 4);
    float* gate2 = (float*)(p + off);   off = align256(off + (size_t)4 * NBKT * BKTCAP * 4);
    int*  slot_tok = (int*)(p + off);   off = align256(off + (size_t)NSLOT_MAX * 4);
    float* slot_gate = (float*)(p + off); off = align256(off + (size_t)NSLOT_MAX * 4);
    int*  back = (int*)(p + off);       off = align256(off + (size_t)2 * NTOK * 4);
    int*  e_of_tile = (int*)(p + off);  off = align256(off + (size_t)NTILE_MAX * 4);
    bf16* spec_g = (bf16*)(p + off);    off = align256(off + (size_t)NSLOT_MAX * DIM * 2);
    bf16* shg   = (bf16*)(p + off);     off = align256(off + (size_t)2 * NTOK * DIM * 2);
    size_t fixed_end = off;
    bf16* Hbuf = (bf16*)(p + fixed_end);
    bf16* xg = spec_g;   // aliased: gather-write -> g1 read -> g2 write -> combine read

    const size_t tile_bytes = (size_t)256 * HID * 2;
    size_t avail = (ws_size > fixed_end) ? (ws_size - fixed_end) : 0;
    int tcap = (int)(avail / tile_bytes);
    if (tcap > NVT) tcap = NVT;

    float* out         = (float*)d_out;
    float* spec_logits = out + (size_t)NTOK * DIM;
    float* spec_probs  = spec_logits + (size_t)NTOK * 4;
    float* topk_idx    = spec_probs  + (size_t)NTOK * 4;
    float* topk_probs  = topk_idx    + (size_t)NTOK * 2;
    float* sh_logits   = topk_probs  + (size_t)NTOK * 2;
    float* sh_probs    = sh_logits   + (size_t)NTOK * 2;

    hipMemsetAsync(cnt2, 0, (size_t)4 * NBKT * 4, stream);
    prep_kernel<<<NCONVB + NTOK / 4, 256, 0, stream>>>(
        spec_w1, sh_w1, spec_w2, sh_w2, w1t, w2t, slot_tok, slot_gate,
        x, gamma, beta, srw, srb, shw, shb, xnb,
        spec_logits, spec_probs, topk_idx, topk_probs, sh_logits, sh_probs,
        gates, cnt2, tok2, gate2);

    if (tcap >= 8) {
        plan_kernel<<<1, 256, 0, stream>>>(cnt2, e_of_tile, tok2, gate2,
                                           slot_tok, slot_gate, back);
        gather_kernel<<<NSLOT_MAX * 96 / 256, 256, 0, stream>>>(xnb, slot_tok, xg);
        int csz = tcap >= 67 ? (NVT + 2) / 3 : (tcap < 64 ? tcap : 64);
        if (csz > tcap) csz = tcap;
        for (int c0 = 0; c0 < NVT; c0 += csz) {
            int n = NVT - c0 < csz ? NVT - c0 : csz;
            gemm1_2p<<<dim3(HID / 256, 2 * n), 512, LDSB1, stream>>>(
                xg, xnb, w1t, spec_b1, sh_b1, e_of_tile, Hbuf, c0);
            gemm2_8p<<<dim3(DIM / 256, n), 512, LDSB, stream>>>(
                Hbuf, w2t, spec_b2, sh_b2, e_of_tile, slot_gate, sh_probs,
                spec_g, shg, c0);
        }
        combine_kernel<<<NTOK * 96 / 256, 256, 0, stream>>>(spec_g, shg, back, out);
    } else {
        // plan B: dense 6-expert loop (reuses spec_g/shg region as H)
        bf16* HB = spec_g;
        for (int e = 0; e < 6; ++e) {
            const bf16* w1p = w1t + (size_t)e * HID * DIM;
            const bf16* w2p = w2t + (size_t)e * DIM * HID;
            const float* b1p = (e < 4) ? spec_b1 + (size_t)e * HID : sh_b1 + (size_t)(e - 4) * HID;
            const float* b2p = (e < 4) ? spec_b2 + (size_t)e * DIM : sh_b2 + (size_t)(e - 4) * DIM;
            gemm1_dense<<<dim3(HID / 128, NTOK / 128), 256, 0, stream>>>(xnb, w1p, b1p, HB);
            gemm2_dense_out<<<dim3(DIM / 128, NTOK / 128), 256, 0, stream>>>(
                HB, w2p, b2p, gates, out, e, e > 0);
        }
    }
}

// Round 18
// 763.876 us; speedup vs baseline: 1.1140x; 1.0007x over previous
//
#include <hip/hip_runtime.h>
#include <hip/hip_bf16.h>
#include <math.h>

#define NTOK 12544
#define DIM 768
#define HID 3072
#define NTILE_MAX 102               // spec 256-row tiles
#define NSLOT_MAX (NTILE_MAX * 256) // 26112 slots
#define NSDT 49                     // NTOK/256 dense row tiles per shared expert
#define NVT (NTILE_MAX + 2 * NSDT)  // 200 virtual 256-row tiles
#define NBKT 64
#define BKTCAP 256
#define LDSB 131072                 // gemm2 (256x256 8-phase)
#define LDSB1 73728                 // gemm1 (128x256 2-phase, 3 slots depth-2)
#define NCONVB 6912                 // conv blocks in prep_kernel (576*12)

typedef __hip_bfloat16 bf16;
typedef __attribute__((ext_vector_type(8))) short short8v;
typedef __attribute__((ext_vector_type(4))) float f32x4;

#define GPTR(p)  ((const __attribute__((address_space(1))) void*)(p))
#define LDSPTR(p) ((__attribute__((address_space(3))) void*)(p))

// ---------------------------------------------------------------- prep: conv (bid<NCONVB) + router_ln (else)
__global__ __launch_bounds__(256) void prep_kernel(
    const float* __restrict__ spec_w1, const float* __restrict__ sh_w1,
    const float* __restrict__ spec_w2, const float* __restrict__ sh_w2,
    bf16* __restrict__ w1t, bf16* __restrict__ w2t,
    int* __restrict__ slot_tok, float* __restrict__ slot_gate,
    const float* __restrict__ x,
    const float* __restrict__ lng, const float* __restrict__ lnb,
    const float* __restrict__ srw, const float* __restrict__ srb,
    const float* __restrict__ shw, const float* __restrict__ shb,
    bf16* __restrict__ xnb,
    float* __restrict__ spec_logits, float* __restrict__ spec_probs,
    float* __restrict__ topk_idx, float* __restrict__ topk_probs,
    float* __restrict__ sh_logits, float* __restrict__ sh_probs,
    float* __restrict__ gates,
    int* __restrict__ cnt2, int* __restrict__ tok2, float* __restrict__ gate2) {
    __shared__ float tile[64][65];
    int bid = blockIdx.x;
    int t = threadIdx.x;
    if (bid < NCONVB) {
        int z = bid / 576, ti = bid % 576;
        if (z == 0 && ti < NTILE_MAX) {
            int s = ti * 256 + t;
            slot_tok[s] = 0; slot_gate[s] = 0.0f;
        }
        const float* src; bf16* dst; int R, C, tr, tc;
        if (z < 6) {
            R = DIM; C = HID;
            src = (z < 4) ? spec_w1 + (size_t)z * R * C : sh_w1 + (size_t)(z - 4) * R * C;
            dst = w1t + (size_t)z * R * C;
            tr = ti % 12; tc = ti / 12;
        } else {
            int e = z - 6;
            R = HID; C = DIM;
            src = (e < 4) ? spec_w2 + (size_t)e * R * C : sh_w2 + (size_t)(e - 4) * R * C;
            dst = w2t + (size_t)e * R * C;
            tr = ti % 48; tc = ti / 48;
        }
        int r0 = tr * 64, c0 = tc * 64;
        int lr = t >> 4, lc = (t & 15) * 4;
        #pragma unroll
        for (int ii = 0; ii < 4; ++ii) {
            float4 v = *(const float4*)&src[(size_t)(r0 + lr + 16 * ii) * C + c0 + lc];
            tile[lc + 0][lr + 16 * ii] = v.x;
            tile[lc + 1][lr + 16 * ii] = v.y;
            tile[lc + 2][lr + 16 * ii] = v.z;
            tile[lc + 3][lr + 16 * ii] = v.w;
        }
        __syncthreads();
        int oc = t >> 4, orr = (t & 15) * 4;
        #pragma unroll
        for (int ii = 0; ii < 4; ++ii) {
            union { ushort4 u4; bf16 h[4]; } pk;
            #pragma unroll
            for (int k = 0; k < 4; ++k)
                pk.h[k] = __float2bfloat16(tile[oc + 16 * ii][orr + k]);
            *(ushort4*)&dst[(size_t)(c0 + oc + 16 * ii) * R + r0 + orr] = pk.u4;
        }
        return;
    }
    int rid = bid - NCONVB;
    int tok = rid * 4 + (t >> 6);
    int bucket = rid & (NBKT - 1);
    int lane = t & 63;
    const float* xr = x + (size_t)tok * DIM;
    bf16* xb = xnb + (size_t)tok * DIM;
    float v[12];
    float s = 0.0f;
    #pragma unroll
    for (int i = 0; i < 6; ++i) {
        float2 xv = *(const float2*)&xr[lane * 2 + 128 * i];
        v[2 * i] = xv.x; v[2 * i + 1] = xv.y;
        s += xv.x + xv.y;
    }
    #pragma unroll
    for (int o = 32; o > 0; o >>= 1) s += __shfl_xor(s, o, 64);
    float mean = s * (1.0f / 768.0f);
    float sq = 0.0f;
    #pragma unroll
    for (int i = 0; i < 12; ++i) { float d = v[i] - mean; sq += d * d; }
    #pragma unroll
    for (int o = 32; o > 0; o >>= 1) sq += __shfl_xor(sq, o, 64);
    float rstd = rsqrtf(sq * (1.0f / 768.0f) + 1e-5f);

    float acc[6] = {0, 0, 0, 0, 0, 0};
    #pragma unroll
    for (int i = 0; i < 6; ++i) {
        int d0 = lane * 2 + 128 * i;
        float xn0 = (v[2 * i]     - mean) * rstd * lng[d0]     + lnb[d0];
        float xn1 = (v[2 * i + 1] - mean) * rstd * lng[d0 + 1] + lnb[d0 + 1];
        union { unsigned u; bf16 h[2]; } pk;
        pk.h[0] = __float2bfloat16(xn0);
        pk.h[1] = __float2bfloat16(xn1);
        *(unsigned*)&xb[d0] = pk.u;
        float4 a = *(const float4*)&srw[d0 * 4];
        float4 b = *(const float4*)&srw[d0 * 4 + 4];
        acc[0] += xn0 * a.x + xn1 * b.x;
        acc[1] += xn0 * a.y + xn1 * b.y;
        acc[2] += xn0 * a.z + xn1 * b.z;
        acc[3] += xn0 * a.w + xn1 * b.w;
        float4 sw = *(const float4*)&shw[d0 * 2];
        acc[4] += xn0 * sw.x + xn1 * sw.z;
        acc[5] += xn0 * sw.y + xn1 * sw.w;
    }
    #pragma unroll
    for (int j = 0; j < 6; ++j) {
        #pragma unroll
        for (int o = 32; o > 0; o >>= 1) acc[j] += __shfl_xor(acc[j], o, 64);
    }
    if (lane == 0) {
        float l[4];
        #pragma unroll
        for (int j = 0; j < 4; ++j) l[j] = acc[j] + srb[j];
        float m = fmaxf(fmaxf(l[0], l[1]), fmaxf(l[2], l[3]));
        float e[4], ssum = 0.0f;
        #pragma unroll
        for (int j = 0; j < 4; ++j) { e[j] = expf(l[j] - m); ssum += e[j]; }
        float inv = 1.0f / ssum;
        float p[4];
        #pragma unroll
        for (int j = 0; j < 4; ++j) p[j] = e[j] * inv;
        int i0 = 0;
        for (int j = 1; j < 4; ++j) if (p[j] > p[i0]) i0 = j;
        int i1 = -1;
        for (int j = 0; j < 4; ++j) {
            if (j == i0) continue;
            if (i1 < 0 || p[j] > p[i1]) i1 = j;
        }
        float sl0 = acc[4] + shb[0], sl1 = acc[5] + shb[1];
        float sm = fmaxf(sl0, sl1);
        float se0 = expf(sl0 - sm), se1 = expf(sl1 - sm);
        float sinv = 1.0f / (se0 + se1);
        float sp0 = se0 * sinv, sp1 = se1 * sinv;

        #pragma unroll
        for (int j = 0; j < 4; ++j) {
            spec_logits[tok * 4 + j] = l[j];
            spec_probs[tok * 4 + j]  = p[j];
        }
        topk_idx[tok * 2 + 0]   = (float)i0;
        topk_idx[tok * 2 + 1]   = (float)i1;
        topk_probs[tok * 2 + 0] = p[i0];
        topk_probs[tok * 2 + 1] = p[i1];
        sh_logits[tok * 2 + 0]  = sl0;
        sh_logits[tok * 2 + 1]  = sl1;
        sh_probs[tok * 2 + 0]   = sp0;
        sh_probs[tok * 2 + 1]   = sp1;
        float gg[6] = {0, 0, 0, 0, sp0, sp1};
        gg[i0] = p[i0];
        gg[i1] = p[i1];
        #pragma unroll
        for (int j = 0; j < 6; ++j) gates[tok * 6 + j] = gg[j];
        int c0 = i0 * NBKT + bucket;
        int pos0 = atomicAdd(&cnt2[c0], 1);
        tok2[c0 * BKTCAP + pos0]  = tok * 2 + 0;
        gate2[c0 * BKTCAP + pos0] = p[i0];
        int c1 = i1 * NBKT + bucket;
        int pos1 = atomicAdd(&cnt2[c1], 1);
        tok2[c1 * BKTCAP + pos1]  = tok * 2 + 1;
        gate2[c1 * BKTCAP + pos1] = p[i1];
    }
}

// ---------------------------------------------------------------- plan: bucket scan, 256-row padded compact
__global__ void plan_kernel(const int* __restrict__ cnt2, int* __restrict__ e_of_tile,
                            const int* __restrict__ tok2, const float* __restrict__ gate2,
                            int* __restrict__ slot_tok, float* __restrict__ slot_gate,
                            int* __restrict__ back) {
    __shared__ int sbase[4 * NBKT];
    __shared__ int offsE[5];
    __shared__ int etot[4];
    int tid = threadIdx.x, lane = tid & 63, wid = tid >> 6;
    int c = cnt2[wid * NBKT + lane];
    int inc = c;
    #pragma unroll
    for (int o = 1; o < 64; o <<= 1) {
        int tv = __shfl_up(inc, o, 64);
        if (lane >= o) inc += tv;
    }
    int exc = inc - c;
    if (lane == 63) etot[wid] = inc;
    __syncthreads();
    if (tid == 0) {
        int o = 0;
        for (int e = 0; e < 4; ++e) { offsE[e] = o; o += (etot[e] + 255) & ~255; }
        offsE[4] = o;
    }
    __syncthreads();
    sbase[tid] = offsE[wid] + exc;
    for (int idx = tid; idx < NTILE_MAX; idx += 256) {
        int s0 = idx * 256, e = -1;
        for (int j = 0; j < 4; ++j)
            if (s0 >= offsE[j] && s0 < offsE[j + 1]) e = j;
        e_of_tile[idx] = e;
    }
    __syncthreads();
    int bs = sbase[tid];
    int cc = cnt2[tid];
    for (int i = 0; i < cc; ++i) {
        int gs = bs + i;
        int tk = tok2[tid * BKTCAP + i];
        slot_tok[gs] = tk >> 1;
        slot_gate[gs] = gate2[tid * BKTCAP + i];
        back[tk] = gs;
    }
}

// ---------------------------------------------------------------- gather: pack spec-slot A rows into xg (aliased w/ spec_g)
__global__ void gather_kernel(const bf16* __restrict__ xnb, const int* __restrict__ slot_tok,
                              bf16* __restrict__ xg) {
    int idx = blockIdx.x * 256 + threadIdx.x;
    int slot = idx / 96;
    int c = (idx % 96) * 8;
    int tok = slot_tok[slot];
    *(short8v*)&xg[(size_t)slot * DIM + c] = *(const short8v*)&xnb[(size_t)tok * DIM + c];
}

// ================================================================ shared MFMA helpers
__device__ __forceinline__ int swz(int off) {
    return off ^ (((off >> 8) & 1) << 4) ^ (((off >> 9) & 1) << 5);
}

__device__ __forceinline__ void stage2(bf16* lds, int base_elems, int wid,
                                       const bf16* s0, const bf16* s1) {
    __builtin_amdgcn_global_load_lds(GPTR(s0), LDSPTR(lds + base_elems + wid * 512), 16, 0, 0);
    __builtin_amdgcn_global_load_lds(GPTR(s1), LDSPTR(lds + base_elems + 4096 + wid * 512), 16, 0, 0);
}

__device__ __forceinline__ void mfma16(const short8v a[4], const short8v b[4], f32x4 (*am)[4]) {
    #pragma unroll
    for (int i = 0; i < 4; ++i)
        #pragma unroll
        for (int j = 0; j < 4; ++j)
            am[i][j] = __builtin_amdgcn_mfma_f32_16x16x32_bf16(a[i], b[j], am[i][j], 0, 0, 0);
}

#define BARRIER() __builtin_amdgcn_s_barrier()
#define VMCNT6() asm volatile("s_waitcnt vmcnt(6)" ::: "memory")
#define VMCNT4() asm volatile("s_waitcnt vmcnt(4)" ::: "memory")
#define VMCNT3() asm volatile("s_waitcnt vmcnt(3)" ::: "memory")
#define VMCNT0() asm volatile("s_waitcnt vmcnt(0)" ::: "memory")

// ================================================================ 256x256 8-phase core (gemm2, refcheck'd R8-R17)
__device__ __forceinline__ void read_a4(const bf16* lds, int buf, int ks, int wm, int mh,
                                        int lane, short8v a[4]) {
    const char* base = (const char*)lds + buf * 32768 + ks * 16384;
    #pragma unroll
    for (int i = 0; i < 4; ++i) {
        int off = (wm * 128 + mh * 64 + i * 16 + (lane & 15)) * 64 + ((lane >> 4) * 16);
        a[i] = *(const short8v*)(base + swz(off));
    }
}

__device__ __forceinline__ void read_b4(const bf16* lds, int buf, int ks, int wn,
                                        int lane, short8v b[4]) {
    const char* base = (const char*)lds + 65536 + buf * 32768 + ks * 16384;
    #pragma unroll
    for (int j = 0; j < 4; ++j) {
        int off = (wn * 64 + j * 16 + (lane & 15)) * 64 + ((lane >> 4) * 16);
        b[j] = *(const short8v*)(base + swz(off));
    }
}

template<int NT>
__device__ __forceinline__ void kloop8p(bf16* lds, const bf16* a0, const bf16* a1,
                                        const bf16* b0, const bf16* b1,
                                        int wm, int wn, int wid, int lane,
                                        f32x4 acc[8][4]) {
    stage2(lds, 0, wid, a0, a1);
    stage2(lds, 32768, wid, b0, b1);
    stage2(lds, 8192, wid, a0 + 32, a1 + 32);
    stage2(lds, 32768 + 8192, wid, b0 + 32, b1 + 32);
    VMCNT4();
    BARRIER();
    for (int t = 0; t < NT; ++t) {
        int buf = t & 1, nb = buf ^ 1;
        bool pre = (t + 1 < NT);
        short8v af[4], bfv[4];
        if (pre) stage2(lds, nb * 16384, wid, a0 + (t + 1) * 64, a1 + (t + 1) * 64);
        read_a4(lds, buf, 0, wm, 0, lane, af);
        read_b4(lds, buf, 0, wn, lane, bfv);
        BARRIER();
        __builtin_amdgcn_s_setprio(1);
        mfma16(af, bfv, &acc[0]);
        __builtin_amdgcn_s_setprio(0);
        BARRIER();
        if (pre) stage2(lds, 32768 + nb * 16384, wid, b0 + (t + 1) * 64, b1 + (t + 1) * 64);
        read_a4(lds, buf, 0, wm, 1, lane, af);
        BARRIER();
        __builtin_amdgcn_s_setprio(1);
        mfma16(af, bfv, &acc[4]);
        __builtin_amdgcn_s_setprio(0);
        if (pre) VMCNT4(); else VMCNT0();
        BARRIER();
        if (pre) stage2(lds, nb * 16384 + 8192, wid, a0 + (t + 1) * 64 + 32, a1 + (t + 1) * 64 + 32);
        read_a4(lds, buf, 1, wm, 0, lane, af);
        read_b4(lds, buf, 1, wn, lane, bfv);
        BARRIER();
        __builtin_amdgcn_s_setprio(1);
        mfma16(af, bfv, &acc[0]);
        __builtin_amdgcn_s_setprio(0);
        BARRIER();
        if (pre) stage2(lds, 32768 + nb * 16384 + 8192, wid, b0 + (t + 1) * 64 + 32, b1 + (t + 1) * 64 + 32);
        read_a4(lds, buf, 1, wm, 1, lane, af);
        BARRIER();
        __builtin_amdgcn_s_setprio(1);
        mfma16(af, bfv, &acc[4]);
        __builtin_amdgcn_s_setprio(0);
        if (pre) VMCNT4();
        BARRIER();
    }
}

// ================================================================ 128x256 2-phase core, 3-slot depth-2 prefetch (gemm1)
// LDS (elems): A slot c at c*4096 ([128][32]); B slot c at 12288 + c*8192 ([256][32]).
__device__ __forceinline__ void read_a4_128(const bf16* lds, int cur, int wm,
                                            int lane, short8v a[4]) {
    const char* base = (const char*)lds + cur * 8192;
    #pragma unroll
    for (int i = 0; i < 4; ++i) {
        int off = (wm * 64 + i * 16 + (lane & 15)) * 64 + ((lane >> 4) * 16);
        a[i] = *(const short8v*)(base + swz(off));
    }
}

__device__ __forceinline__ void read_b4_128(const bf16* lds, int cur, int wn,
                                            int lane, short8v b[4]) {
    const char* base = (const char*)lds + 24576 + cur * 16384;
    #pragma unroll
    for (int j = 0; j < 4; ++j) {
        int off = (wn * 64 + j * 16 + (lane & 15)) * 64 + ((lane >> 4) * 16);
        b[j] = *(const short8v*)(base + swz(off));
    }
}

// issue one K-32 slice s into slot c (3 loads/thread: 1 A + 2 B)
__device__ __forceinline__ void issue_slice(bf16* lds, int c, int wid,
                                            const bf16* aA, const bf16* b0, const bf16* b1,
                                            int s) {
    __builtin_amdgcn_global_load_lds(GPTR(aA + s * 32),
                                     LDSPTR(lds + c * 4096 + wid * 512), 16, 0, 0);
    stage2(lds, 12288 + c * 8192, wid, b0 + s * 32, b1 + s * 32);
}

template<int NS>
__device__ __forceinline__ void kloop2p(bf16* lds, const bf16* aA,
                                        const bf16* b0, const bf16* b1,
                                        int wm, int wn, int wid, int lane,
                                        f32x4 acc[4][4]) {
    issue_slice(lds, 0, wid, aA, b0, b1, 0);
    issue_slice(lds, 1, wid, aA, b0, b1, 1);
    int cur = 0;
    for (int s = 0; s < NS; ++s) {
        int pf = cur + 2; if (pf >= 3) pf -= 3;   // slot for slice s+2
        if (s + 2 < NS) issue_slice(lds, pf, wid, aA, b0, b1, s + 2);
        // wait for slice s: newer in flight = 3 per pending newer slice
        if (s + 2 < NS)      VMCNT6();
        else if (s + 1 < NS) VMCNT3();
        else                 VMCNT0();
        BARRIER();
        short8v av[4], bv[4];
        read_a4_128(lds, cur, wm, lane, av);
        read_b4_128(lds, cur, wn, lane, bv);
        __builtin_amdgcn_s_setprio(1);
        mfma16(av, bv, &acc[0]);
        __builtin_amdgcn_s_setprio(0);
        BARRIER();
        ++cur; if (cur == 3) cur = 0;
    }
}

__device__ __forceinline__ float gelu_exact(float v) {
    return 0.5f * v * (1.0f + erff(v * 0.70710678118654752f));
}

// tanh-form GELU via hw exp2 (7 VALU ops, max |err| ~3e-4 vs exact)
__device__ __forceinline__ float gelu_tanh(float x) {
    float x2 = x * x;
    float un = x * fmaf(x2, -0.10291313f, -2.30218576f);
    float e = exp2f(un);
    return x * __builtin_amdgcn_rcpf(1.0f + e);
}

// ---------------------------------------------------------------- GEMM1 2-phase 128x256 depth-2 (tanh-GELU epilogue)
__global__ __launch_bounds__(512, 2) void gemm1_2p(
    const bf16* __restrict__ xg, const bf16* __restrict__ xnb,
    const bf16* __restrict__ w1t,
    const float* __restrict__ spec_b1, const float* __restrict__ sh_b1,
    const int* __restrict__ e_of_tile,
    bf16* __restrict__ Hbuf, int y_base) {
    extern __shared__ bf16 lds[];
    int bx = blockIdx.x, by = blockIdx.y;
    int lt = by >> 1, half = by & 1;
    int y = y_base + lt;
    int tid = threadIdx.x, wid = tid >> 6, lane = tid & 63;
    int wm = wid >> 2, wn = wid & 3;
    int PA = tid;
    int LA = PA ^ ((PA >> 4) & 1) ^ (((PA >> 5) & 1) << 1);
    int ra = LA >> 2, ca = (LA & 3) * 8;
    int P0c = tid, P1c = 512 + tid;
    int L0 = P0c ^ ((P0c >> 4) & 1) ^ (((P0c >> 5) & 1) << 1);
    int L1 = P1c ^ ((P1c >> 4) & 1) ^ (((P1c >> 5) & 1) << 1);
    int rb0 = L0 >> 2, cb0 = (L0 & 3) * 8;
    int rb1 = L1 >> 2, cb1 = (L1 & 3) * 8;

    const bf16 *abase, *Bw;
    const float* bias;
    if (y < NTILE_MAX) {
        int e = e_of_tile[y];
        if (e < 0) return;
        abase = xg + (size_t)(y * 256 + half * 128) * DIM;
        Bw = w1t + (size_t)e * HID * DIM;
        bias = spec_b1 + (size_t)e * HID;
    } else {
        int ys = y - NTILE_MAX;
        int z = ys / NSDT, ry = ys % NSDT;
        abase = xnb + (size_t)(ry * 256 + half * 128) * DIM;
        Bw = w1t + (size_t)(4 + z) * HID * DIM;
        bias = sh_b1 + (size_t)z * HID;
    }
    const bf16* aA = abase + (size_t)ra * DIM + ca;
    const bf16* b0 = Bw + (size_t)(bx * 256 + rb0) * DIM + cb0;
    const bf16* b1 = Bw + (size_t)(bx * 256 + rb1) * DIM + cb1;

    f32x4 acc[4][4] = {};
    kloop2p<DIM / 32>(lds, aA, b0, b1, wm, wn, wid, lane, acc);

    bf16* hb = Hbuf + (size_t)(lt * 256 + half * 128) * HID;
    int fr = lane & 15, fq = lane >> 4;
    int cb = bx * 256 + wn * 64;
    float bvv[4];
    #pragma unroll
    for (int j = 0; j < 4; ++j) bvv[j] = bias[cb + j * 16 + fr];
    #pragma unroll
    for (int i = 0; i < 4; ++i) {
        #pragma unroll
        for (int rr = 0; rr < 4; ++rr) {
            int row = wm * 64 + i * 16 + fq * 4 + rr;
            bf16* hr = hb + (size_t)row * HID + cb + fr;
            #pragma unroll
            for (int j = 0; j < 4; ++j)
                hr[j * 16] = __float2bfloat16(gelu_tanh(acc[i][j][rr] + bvv[j]));
        }
    }
}

// ---------------------------------------------------------------- GEMM2 8-phase 256x256 (row-major store epilogue)
__global__ __launch_bounds__(512, 2) void gemm2_8p(
    const bf16* __restrict__ Hbuf, const bf16* __restrict__ w2t,
    const float* __restrict__ spec_b2, const float* __restrict__ sh_b2,
    const int* __restrict__ e_of_tile, const float* __restrict__ slot_gate,
    const float* __restrict__ sh_probs,
    bf16* __restrict__ spec_g, bf16* __restrict__ shg, int y_base) {
    extern __shared__ bf16 lds[];
    int bx = blockIdx.x, by = blockIdx.y;
    int y = by + y_base;
    int tid = threadIdx.x, wid = tid >> 6, lane = tid & 63;
    int wm = wid >> 2, wn = wid & 3;
    int P0c = tid, P1c = 512 + tid;
    int L0 = P0c ^ ((P0c >> 4) & 1) ^ (((P0c >> 5) & 1) << 1);
    int L1 = P1c ^ ((P1c >> 4) & 1) ^ (((P1c >> 5) & 1) << 1);
    int r0 = L0 >> 2, c0 = (L0 & 3) * 8;
    int r1 = L1 >> 2, c1 = (L1 & 3) * 8;

    const bf16 *Bw;
    const float* bias;
    bf16* obase;
    bool grouped = (y < NTILE_MAX);
    int z = 0, ry = 0;
    if (grouped) {
        int e = e_of_tile[y];
        if (e < 0) return;
        Bw = w2t + (size_t)e * DIM * HID;
        bias = spec_b2 + (size_t)e * DIM;
        obase = spec_g + (size_t)y * 256 * DIM;
    } else {
        int ys = y - NTILE_MAX;
        z = ys / NSDT; ry = ys % NSDT;
        Bw = w2t + (size_t)(4 + z) * DIM * HID;
        bias = sh_b2 + (size_t)z * DIM;
        obase = shg + (size_t)(z * NTOK + ry * 256) * DIM;
    }
    const bf16* Ah = Hbuf + (size_t)by * 256 * HID;
    const bf16* a0 = Ah + (size_t)r0 * HID + c0;
    const bf16* a1 = Ah + (size_t)r1 * HID + c1;
    const bf16* b0 = Bw + (size_t)(bx * 256 + r0) * HID + c0;
    const bf16* b1 = Bw + (size_t)(bx * 256 + r1) * HID + c1;

    f32x4 acc[8][4] = {};
    kloop8p<HID / 64>(lds, a0, a1, b0, b1, wm, wn, wid, lane, acc);

    int fr = lane & 15, fq = lane >> 4;
    int cb = bx * 256 + wn * 64;
    float bvv[4];
    #pragma unroll
    for (int j = 0; j < 4; ++j) bvv[j] = bias[cb + j * 16 + fr];
    #pragma unroll
    for (int ii = 0; ii < 8; ++ii) {
        #pragma unroll
        for (int rr = 0; rr < 4; ++rr) {
            int row = wm * 128 + (ii >> 2) * 64 + (ii & 3) * 16 + fq * 4 + rr;
            float g = grouped ? slot_gate[y * 256 + row]
                              : sh_probs[(size_t)(ry * 256 + row) * 2 + z];
            bf16* orow = obase + (size_t)row * DIM + cb + fr;
            #pragma unroll
            for (int j = 0; j < 4; ++j)
                orow[j * 16] = __float2bfloat16(g * (acc[ii][j][rr] + bvv[j]));
        }
    }
}

// ---------------------------------------------------------------- plan-B dense fallback (128^2 m97, known-good)
__device__ __forceinline__ void stage_tile(const bf16* __restrict__ g, int ldg,
                                           bf16* lds, int tid) {
    int wave = tid >> 6, lane = tid & 63;
    #pragma unroll
    for (int q = 0; q < 2; ++q) {
        int chunk = wave * 2 + q;
        int row = chunk * 16 + (lane >> 2);
        int col = (lane & 3) * 8;
        __builtin_amdgcn_global_load_lds(GPTR(g + (size_t)row * ldg + col),
                                         LDSPTR(lds + chunk * 512), 16, 0, 0);
    }
}

__device__ __forceinline__ void mfma_step(const bf16* As, const bf16* Bs,
                                          int wr, int wc, int fr, int fq, f32x4 acc[4][4]) {
    short8v a[4], b[4];
    #pragma unroll
    for (int i = 0; i < 4; ++i) {
        a[i] = *(const short8v*)&As[(wr * 64 + i * 16 + fr) * 32 + fq * 8];
        b[i] = *(const short8v*)&Bs[(wc * 64 + i * 16 + fr) * 32 + fq * 8];
    }
    #pragma unroll
    for (int i = 0; i < 4; ++i)
        #pragma unroll
        for (int j = 0; j < 4; ++j)
            acc[i][j] = __builtin_amdgcn_mfma_f32_16x16x32_bf16(a[i], b[j], acc[i][j], 0, 0, 0);
}

__global__ __launch_bounds__(256) void gemm1_dense(
    const bf16* __restrict__ A, const bf16* __restrict__ BT,
    const float* __restrict__ bias, bf16* __restrict__ H) {
    __shared__ bf16 As[128 * 32];
    __shared__ bf16 Bs[128 * 32];
    int tid = threadIdx.x;
    int wid = tid >> 6, lane = tid & 63;
    int wr = wid >> 1, wc = wid & 1;
    int fr = lane & 15, fq = lane >> 4;
    const bf16* Ag = A + (size_t)(blockIdx.y * 128) * DIM;
    const bf16* Bg = BT + (size_t)(blockIdx.x * 128) * DIM;
    f32x4 acc[4][4] = {};
    for (int k0 = 0; k0 < DIM; k0 += 32) {
        stage_tile(Ag + k0, DIM, As, tid);
        stage_tile(Bg + k0, DIM, Bs, tid);
        __syncthreads();
        mfma_step(As, Bs, wr, wc, fr, fq, acc);
        __syncthreads();
    }
    int rbase = blockIdx.y * 128 + wr * 64;
    int cbase = blockIdx.x * 128 + wc * 64;
    #pragma unroll
    for (int j = 0; j < 4; ++j) {
        int col = cbase + j * 16 + fr;
        float bv = bias[col];
        #pragma unroll
        for (int i = 0; i < 4; ++i)
            #pragma unroll
            for (int r = 0; r < 4; ++r) {
                int row = rbase + i * 16 + fq * 4 + r;
                H[(size_t)row * HID + col] = __float2bfloat16(gelu_exact(acc[i][j][r] + bv));
            }
    }
}

__global__ __launch_bounds__(256) void gemm2_dense_out(
    const bf16* __restrict__ A, const bf16* __restrict__ BT,
    const float* __restrict__ bias, const float* __restrict__ gates,
    float* __restrict__ out, int gidx, int accum) {
    __shared__ bf16 As[128 * 32];
    __shared__ bf16 Bs[128 * 32];
    int tid = threadIdx.x;
    int wid = tid >> 6, lane = tid & 63;
    int wr = wid >> 1, wc = wid & 1;
    int fr = lane & 15, fq = lane >> 4;
    const bf16* Ag = A + (size_t)(blockIdx.y * 128) * HID;
    const bf16* Bg = BT + (size_t)(blockIdx.x * 128) * HID;
    f32x4 acc[4][4] = {};
    for (int k0 = 0; k0 < HID; k0 += 32) {
        stage_tile(Ag + k0, HID, As, tid);
        stage_tile(Bg + k0, HID, Bs, tid);
        __syncthreads();
        mfma_step(As, Bs, wr, wc, fr, fq, acc);
        __syncthreads();
    }
    int rbase = blockIdx.y * 128 + wr * 64;
    int cbase = blockIdx.x * 128 + wc * 64;
    #pragma unroll
    for (int j = 0; j < 4; ++j) {
        int col = cbase + j * 16 + fr;
        float bv = bias[col];
        #pragma unroll
        for (int i = 0; i < 4; ++i)
            #pragma unroll
            for (int r = 0; r < 4; ++r) {
                int row = rbase + i * 16 + fq * 4 + r;
                float g = gates[(size_t)row * 6 + gidx];
                float v = g * (acc[i][j][r] + bv);
                size_t idx = (size_t)row * DIM + col;
                out[idx] = accum ? out[idx] + v : v;
            }
    }
}

// ---------------------------------------------------------------- combine
__global__ void combine_kernel(const bf16* __restrict__ spec_g, const bf16* __restrict__ shg,
                               const int* __restrict__ back, float* __restrict__ out) {
    int idx = blockIdx.x * 256 + threadIdx.x;
    int tok = idx / 96;
    int c = (idx % 96) * 8;
    int b0 = back[2 * tok], b1 = back[2 * tok + 1];
    short8v q0 = *(const short8v*)&spec_g[(size_t)b0 * DIM + c];
    short8v q1 = *(const short8v*)&spec_g[(size_t)b1 * DIM + c];
    short8v s0 = *(const short8v*)&shg[(size_t)tok * DIM + c];
    short8v s1 = *(const short8v*)&shg[(size_t)(NTOK + tok) * DIM + c];
    float o[8];
    #pragma unroll
    for (int k = 0; k < 8; ++k) {
        float f0 = __uint_as_float((unsigned)(unsigned short)q0[k] << 16);
        float f1 = __uint_as_float((unsigned)(unsigned short)q1[k] << 16);
        float f2 = __uint_as_float((unsigned)(unsigned short)s0[k] << 16);
        float f3 = __uint_as_float((unsigned)(unsigned short)s1[k] << 16);
        o[k] = f0 + f1 + f2 + f3;
    }
    float* op = out + (size_t)tok * DIM + c;
    *(float4*)(op)     = *(const float4*)(o);
    *(float4*)(op + 4) = *(const float4*)(o + 4);
}

// ---------------------------------------------------------------- launch
static inline size_t align256(size_t x) { return (x + 255) & ~(size_t)255; }

extern "C" void kernel_launch(void* const* d_in, const int* in_sizes, int n_in,
                              void* d_out, int out_size, void* d_ws, size_t ws_size,
                              hipStream_t stream) {
    const float* x      = (const float*)d_in[0];
    const float* gamma  = (const float*)d_in[1];
    const float* beta   = (const float*)d_in[2];
    const float* srw    = (const float*)d_in[3];
    const float* srb    = (const float*)d_in[4];
    const float* spec_w1 = (const float*)d_in[5];
    const float* spec_b1 = (const float*)d_in[6];
    const float* spec_w2 = (const float*)d_in[7];
    const float* spec_b2 = (const float*)d_in[8];
    const float* shw    = (const float*)d_in[9];
    const float* shb    = (const float*)d_in[10];
    const float* sh_w1  = (const float*)d_in[11];
    const float* sh_b1  = (const float*)d_in[12];
    const float* sh_w2  = (const float*)d_in[13];
    const float* sh_b2  = (const float*)d_in[14];

    char* p = (char*)d_ws;
    size_t off = 0;
    bf16* xnb = (bf16*)(p + off);       off = align256(off + (size_t)NTOK * DIM * 2);
    bf16* w1t = (bf16*)(p + off);       off = align256(off + (size_t)6 * HID * DIM * 2);
    bf16* w2t = (bf16*)(p + off);       off = align256(off + (size_t)6 * DIM * HID * 2);
    int*  cnt2 = (int*)(p + off);       off = align256(off + (size_t)4 * NBKT * 4);
    float* gates = (float*)(p + off);   off = align256(off + (size_t)NTOK * 6 * 4);
    int*  tok2 = (int*)(p + off);       off = align256(off + (size_t)4 * NBKT * BKTCAP * 4);
    float* gate2 = (float*)(p + off);   off = align256(off + (size_t)4 * NBKT * BKTCAP * 4);
    int*  slot_tok = (int*)(p + off);   off = align256(off + (size_t)NSLOT_MAX * 4);
    float* slot_gate = (float*)(p + off); off = align256(off + (size_t)NSLOT_MAX * 4);
    int*  back = (int*)(p + off);       off = align256(off + (size_t)2 * NTOK * 4);
    int*  e_of_tile = (int*)(p + off);  off = align256(off + (size_t)NTILE_MAX * 4);
    bf16* spec_g = (bf16*)(p + off);    off = align256(off + (size_t)NSLOT_MAX * DIM * 2);
    bf16* shg   = (bf16*)(p + off);     off = align256(off + (size_t)2 * NTOK * DIM * 2);
    size_t fixed_end = off;
    bf16* Hbuf = (bf16*)(p + fixed_end);
    bf16* xg = spec_g;   // aliased: gather-write -> g1 read -> g2 write -> combine read

    const size_t tile_bytes = (size_t)256 * HID * 2;
    size_t avail = (ws_size > fixed_end) ? (ws_size - fixed_end) : 0;
    int tcap = (int)(avail / tile_bytes);
    if (tcap > NVT) tcap = NVT;

    float* out         = (float*)d_out;
    float* spec_logits = out + (size_t)NTOK * DIM;
    float* spec_probs  = spec_logits + (size_t)NTOK * 4;
    float* topk_idx    = spec_probs  + (size_t)NTOK * 4;
    float* topk_probs  = topk_idx    + (size_t)NTOK * 2;
    float* sh_logits   = topk_probs  + (size_t)NTOK * 2;
    float* sh_probs    = sh_logits   + (size_t)NTOK * 2;

    hipMemsetAsync(cnt2, 0, (size_t)4 * NBKT * 4, stream);
    prep_kernel<<<NCONVB + NTOK / 4, 256, 0, stream>>>(
        spec_w1, sh_w1, spec_w2, sh_w2, w1t, w2t, slot_tok, slot_gate,
        x, gamma, beta, srw, srb, shw, shb, xnb,
        spec_logits, spec_probs, topk_idx, topk_probs, sh_logits, sh_probs,
        gates, cnt2, tok2, gate2);

    if (tcap >= 8) {
        plan_kernel<<<1, 256, 0, stream>>>(cnt2, e_of_tile, tok2, gate2,
                                           slot_tok, slot_gate, back);
        gather_kernel<<<NSLOT_MAX * 96 / 256, 256, 0, stream>>>(xnb, slot_tok, xg);
        int csz = tcap >= 67 ? (NVT + 2) / 3 : (tcap < 64 ? tcap : 64);
        if (csz > tcap) csz = tcap;
        for (int c0 = 0; c0 < NVT; c0 += csz) {
            int n = NVT - c0 < csz ? NVT - c0 : csz;
            gemm1_2p<<<dim3(HID / 256, 2 * n), 512, LDSB1, stream>>>(
                xg, xnb, w1t, spec_b1, sh_b1, e_of_tile, Hbuf, c0);
            gemm2_8p<<<dim3(DIM / 256, n), 512, LDSB, stream>>>(
                Hbuf, w2t, spec_b2, sh_b2, e_of_tile, slot_gate, sh_probs,
                spec_g, shg, c0);
        }
        combine_kernel<<<NTOK * 96 / 256, 256, 0, stream>>>(spec_g, shg, back, out);
    } else {
        // plan B: dense 6-expert loop (reuses spec_g/shg region as H)
        bf16* HB = spec_g;
        for (int e = 0; e < 6; ++e) {
            const bf16* w1p = w1t + (size_t)e * HID * DIM;
            const bf16* w2p = w2t + (size_t)e * DIM * HID;
            const float* b1p = (e < 4) ? spec_b1 + (size_t)e * HID : sh_b1 + (size_t)(e - 4) * HID;
            const float* b2p = (e < 4) ? spec_b2 + (size_t)e * DIM : sh_b2 + (size_t)(e - 4) * DIM;
            gemm1_dense<<<dim3(HID / 128, NTOK / 128), 256, 0, stream>>>(xnb, w1p, b1p, HB);
            gemm2_dense_out<<<dim3(DIM / 128, NTOK / 128), 256, 0, stream>>>(
                HB, w2p, b2p, gates, out, e, e > 0);
        }
    }
}